// Round 4
// baseline (437.672 us; speedup 1.0000x reference)
//
#include <hip/hip_runtime.h>

// ---------------- problem constants ----------------
constexpr int cN     = 20000;
constexpr int cT     = 8;
constexpr int cFIN   = 64;
constexpr int cHEADS = 4;
constexpr int cF     = 32;
constexpr int cHID   = 128;        // cHEADS * cF
constexpr int cE     = 320000;
constexpr int cET    = cE + cN;    // edges + self loops
constexpr int cR     = cN * cT;    // 160000 batched rows, rho = t*N + n (t-major)
constexpr float cLEAKY = 0.2f;
constexpr float cL2E = 1.44269504088896340736f;   // log2(e)

typedef __attribute__((ext_vector_type(8))) short bf16x8;   // MFMA A/B frag
typedef __attribute__((ext_vector_type(4))) float f32x4;    // MFMA C/D frag

static __device__ __forceinline__ unsigned short f2bfu(float f) {
    unsigned int u;
    __builtin_memcpy(&u, &f, 4);
    u += 0x7FFFu + ((u >> 16) & 1u);
    return (unsigned short)(u >> 16);
}
static __device__ __forceinline__ void unpack2(unsigned int v, float& lo, float& hi) {
    unsigned int ul = v << 16, uh = v & 0xFFFF0000u;
    __builtin_memcpy(&lo, &ul, 4);
    __builtin_memcpy(&hi, &uh, 4);
}
static __device__ __forceinline__ unsigned int pack2(float lo, float hi) {
    unsigned int ul, uh;
    __builtin_memcpy(&ul, &lo, 4);
    __builtin_memcpy(&uh, &hi, 4);
    ul += 0x7FFFu + ((ul >> 16) & 1u);
    uh += 0x7FFFu + ((uh >> 16) & 1u);
    return (ul >> 16) | (uh & 0xFFFF0000u);
}
static __device__ __forceinline__ void fma8(uint4 r, float w, float* acc) {
    float lo, hi;
    unpack2(r.x, lo, hi); acc[0] += w * lo; acc[1] += w * hi;
    unpack2(r.y, lo, hi); acc[2] += w * lo; acc[3] += w * hi;
    unpack2(r.z, lo, hi); acc[4] += w * lo; acc[5] += w * hi;
    unpack2(r.w, lo, hi); acc[6] += w * lo; acc[7] += w * hi;
}
static __device__ __forceinline__ void finish8(const float* acc, float den,
                                               const float* bias, int j, float* r) {
    float inv = 1.f / (den + 1e-16f);
    float4 b0 = *(const float4*)(bias + 8 * j);
    float4 b1 = *(const float4*)(bias + 8 * j + 4);
    float v;
    v = acc[0] * inv + b0.x; r[0] = (v > 0.f) ? v : expm1f(v);
    v = acc[1] * inv + b0.y; r[1] = (v > 0.f) ? v : expm1f(v);
    v = acc[2] * inv + b0.z; r[2] = (v > 0.f) ? v : expm1f(v);
    v = acc[3] * inv + b0.w; r[3] = (v > 0.f) ? v : expm1f(v);
    v = acc[4] * inv + b1.x; r[4] = (v > 0.f) ? v : expm1f(v);
    v = acc[5] * inv + b1.y; r[5] = (v > 0.f) ? v : expm1f(v);
    v = acc[6] * inv + b1.z; r[6] = (v > 0.f) ? v : expm1f(v);
    v = acc[7] * inv + b1.w; r[7] = (v > 0.f) ? v : expm1f(v);
}

// ---------------- fused weight conversion + degree count ----------------
__global__ void cvt_deg_kernel(const float* W1, const float* W2, const float* lw1,
                               const int* ei, unsigned short* W1b, unsigned short* W2b,
                               unsigned short* lw1b, int* deg) {
    int i = blockIdx.x * 256 + threadIdx.x;
    if (i < cHID * cFIN)                      W1b[i] = f2bfu(W1[i]);
    else if (i < cHID * cFIN + cHID * cHID)   W2b[i - cHID * cFIN] = f2bfu(W2[i - cHID * cFIN]);
    else if (i < cHID * cFIN + cHID * cHID + cF * cHID)
        lw1b[i - cHID * cFIN - cHID * cHID] = f2bfu(lw1[i - cHID * cFIN - cHID * cHID]);
    if (i < cE) atomicAdd(&deg[ei[cE + i]], 1);
}

// LDS-staged scan; self-loop (+1) folded into the read so deg_init is gone.
__global__ void scan_kernel(const int* deg, int* offs, int* cur) {
    __shared__ int sdeg[79 * 256];     // 20224 >= cN
    __shared__ int lds[256];
    int tid = threadIdx.x;
    #pragma unroll 4
    for (int k = 0; k < 79; k++) {
        int idx = k * 256 + tid;
        sdeg[idx] = (idx < cN) ? deg[idx] + 1 : 0;
    }
    __syncthreads();
    const int CH = 79;
    int base = tid * CH;
    int tot = 0;
    #pragma unroll 8
    for (int j = 0; j < CH; j++) tot += sdeg[base + j];
    lds[tid] = tot;
    __syncthreads();
    for (int off = 1; off < 256; off <<= 1) {
        int v = (tid >= off) ? lds[tid - off] : 0;
        __syncthreads();
        lds[tid] += v;
        __syncthreads();
    }
    int run = lds[tid] - tot;
    for (int j = 0; j < CH; j++) {
        int idx = base + j;
        if (idx < cN) { offs[idx] = run; cur[idx] = run; run += sdeg[idx]; }
    }
    if (tid == 255) offs[cN] = lds[255];
}
__global__ void scatter_kernel(const int* ei, int* cur, int* csr) {
    int e = blockIdx.x * blockDim.x + threadIdx.x;
    if (e >= cET) return;
    int s, d;
    if (e < cE) { s = ei[e]; d = ei[cE + e]; }
    else        { s = e - cE; d = s; }
    int pos = atomicAdd(&cur[d], 1);
    csr[pos] = s;
}

// ---------------- GEMM1 (fused fp32->bf16 cvt of x) + scores ----------------
// scores written pre-scaled by log2(e) so agg uses bare v_exp_f32 (exp2).
__global__ __launch_bounds__(256) void gemm1_fused_kernel(
        const float* __restrict__ x, const unsigned short* __restrict__ W,
        const float* __restrict__ a_src, const float* __restrict__ a_dst,
        unsigned short* __restrict__ hb, float* __restrict__ es, float* __restrict__ ed) {
    __shared__ float hl[64][132];
    int tid  = threadIdx.x;
    int wave = tid >> 6;
    int lane = tid & 63;
    int q    = lane >> 4;
    int mi   = lane & 15;
    int m0   = blockIdx.x * 64 + wave * 16;

    int rho = m0 + mi;
    int t = rho / cN;
    int n = rho - t * cN;
    const float* xr = x + (size_t)n * (cT * cFIN) + t * cFIN;

    bf16x8 afrag[2];
    #pragma unroll
    for (int s = 0; s < 2; s++) {
        float4 v0 = *(const float4*)(xr + s * 32 + q * 8);
        float4 v1 = *(const float4*)(xr + s * 32 + q * 8 + 4);
        bf16x8 f;
        f[0] = (short)f2bfu(v0.x); f[1] = (short)f2bfu(v0.y);
        f[2] = (short)f2bfu(v0.z); f[3] = (short)f2bfu(v0.w);
        f[4] = (short)f2bfu(v1.x); f[5] = (short)f2bfu(v1.y);
        f[6] = (short)f2bfu(v1.z); f[7] = (short)f2bfu(v1.w);
        afrag[s] = f;
    }

    f32x4 acc[8];
    #pragma unroll
    for (int ct = 0; ct < 8; ct++) acc[ct] = (f32x4){0.f, 0.f, 0.f, 0.f};
    #pragma unroll
    for (int ct = 0; ct < 8; ct++) {
        int c = ct * 16 + mi;
        #pragma unroll
        for (int s = 0; s < 2; s++) {
            bf16x8 bfrag = *(const bf16x8*)(W + (size_t)c * cFIN + s * 32 + q * 8);
            acc[ct] = __builtin_amdgcn_mfma_f32_16x16x32_bf16(afrag[s], bfrag, acc[ct], 0, 0, 0);
        }
    }

    #pragma unroll
    for (int ct = 0; ct < 8; ct++)
        #pragma unroll
        for (int r = 0; r < 4; r++)
            hl[wave * 16 + q * 4 + r][ct * 16 + mi] = acc[ct][r];
    __syncthreads();

    {
        int r2 = tid & 63;
        int hd = tid >> 6;
        int rg = blockIdx.x * 64 + r2;
        const float* hr = &hl[r2][hd * cF];
        const float* sa = a_src + hd * cF;
        const float* da = a_dst + hd * cF;
        float s1 = 0.f, s2 = 0.f;
        #pragma unroll 8
        for (int f = 0; f < cF; f++) {
            float hv = hr[f];
            s1 += hv * sa[f];
            s2 += hv * da[f];
        }
        es[rg * cHEADS + hd] = s1 * cL2E;
        ed[rg * cHEADS + hd] = s2 * cL2E;
    }

    size_t base = (size_t)blockIdx.x * 64 * cHID;
    #pragma unroll
    for (int it = 0; it < 8; it++) {
        int g   = tid + it * 256;
        int row = g >> 5;
        int c4  = (g & 31) * 4;
        float4 v = *(const float4*)&hl[row][c4];
        unsigned int p0 = pack2(v.x, v.y), p1 = pack2(v.z, v.w);
        *(uint2*)(hb + base + (size_t)row * cHID + c4) = make_uint2(p0, p1);
    }
}

// ---------------- dual-plane agg core ----------------
// Processes planes tA and tB (same node, same csr list) together: doubles the
// independent loads in flight per thread (latency hiding) and halves csr/offs
// metadata traffic. Scores pre-scaled by log2(e); w = exp2(leaky(es+ed)).
static __device__ __forceinline__ void agg_core2(
        const unsigned short* __restrict__ hb, const float* __restrict__ es,
        const float* __restrict__ ed, const int* __restrict__ offs,
        const int* __restrict__ csr, const float* __restrict__ bias,
        int tA, int tB, int n, int j, float* rA, float* rB) {
    int head = j >> 2;
    int s0 = offs[n], s1 = offs[n + 1];
    float ednA = ed[(size_t)(tA * cN + n) * cHEADS + head];
    float ednB = ed[(size_t)(tB * cN + n) * cHEADS + head];
    const char* hpA = (const char*)(hb + (size_t)tA * cN * cHID);
    const char* hpB = (const char*)(hb + (size_t)tB * cN * cHID);
    const char* epA = (const char*)(es + (size_t)tA * cN * cHEADS);
    const char* epB = (const char*)(es + (size_t)tB * cN * cHEADS);
    const char* cc  = (const char*)csr;
    unsigned jo = (unsigned)j * 16u;
    unsigned ho = (unsigned)head * 4u;

    float accA[8] = {}, accB[8] = {};
    float denA = 0.f, denB = 0.f;
    int i = s0;
    for (; i + 3 < s1; i += 4) {
        unsigned io = (unsigned)i * 4u;
        int sa = *(const int*)(cc + io);
        int sb = *(const int*)(cc + io + 4u);
        int sc = *(const int*)(cc + io + 8u);
        int sd = *(const int*)(cc + io + 12u);
        unsigned oa = ((unsigned)sa) << 8, ob = ((unsigned)sb) << 8;
        unsigned oc = ((unsigned)sc) << 8, od = ((unsigned)sd) << 8;
        uint4 raA = *(const uint4*)(hpA + oa + jo);
        uint4 rbA = *(const uint4*)(hpA + ob + jo);
        uint4 rcA = *(const uint4*)(hpA + oc + jo);
        uint4 rdA = *(const uint4*)(hpA + od + jo);
        uint4 raB = *(const uint4*)(hpB + oa + jo);
        uint4 rbB = *(const uint4*)(hpB + ob + jo);
        uint4 rcB = *(const uint4*)(hpB + oc + jo);
        uint4 rdB = *(const uint4*)(hpB + od + jo);
        unsigned ea4 = (((unsigned)sa) << 4) + ho, eb4 = (((unsigned)sb) << 4) + ho;
        unsigned ec4 = (((unsigned)sc) << 4) + ho, ed4 = (((unsigned)sd) << 4) + ho;
        float eaA = *(const float*)(epA + ea4) + ednA;
        float ebA = *(const float*)(epA + eb4) + ednA;
        float ecA = *(const float*)(epA + ec4) + ednA;
        float eeA = *(const float*)(epA + ed4) + ednA;
        float eaB = *(const float*)(epB + ea4) + ednB;
        float ebB = *(const float*)(epB + eb4) + ednB;
        float ecB = *(const float*)(epB + ec4) + ednB;
        float eeB = *(const float*)(epB + ed4) + ednB;
        eaA = (eaA >= 0.f) ? eaA : cLEAKY * eaA;
        ebA = (ebA >= 0.f) ? ebA : cLEAKY * ebA;
        ecA = (ecA >= 0.f) ? ecA : cLEAKY * ecA;
        eeA = (eeA >= 0.f) ? eeA : cLEAKY * eeA;
        eaB = (eaB >= 0.f) ? eaB : cLEAKY * eaB;
        ebB = (ebB >= 0.f) ? ebB : cLEAKY * ebB;
        ecB = (ecB >= 0.f) ? ecB : cLEAKY * ecB;
        eeB = (eeB >= 0.f) ? eeB : cLEAKY * eeB;
        float waA = __builtin_amdgcn_exp2f(eaA), wbA = __builtin_amdgcn_exp2f(ebA);
        float wcA = __builtin_amdgcn_exp2f(ecA), wdA = __builtin_amdgcn_exp2f(eeA);
        float waB = __builtin_amdgcn_exp2f(eaB), wbB = __builtin_amdgcn_exp2f(ebB);
        float wcB = __builtin_amdgcn_exp2f(ecB), wdB = __builtin_amdgcn_exp2f(eeB);
        denA += waA; denA += wbA; denA += wcA; denA += wdA;
        denB += waB; denB += wbB; denB += wcB; denB += wdB;
        fma8(raA, waA, accA); fma8(rbA, wbA, accA);
        fma8(rcA, wcA, accA); fma8(rdA, wdA, accA);
        fma8(raB, waB, accB); fma8(rbB, wbB, accB);
        fma8(rcB, wcB, accB); fma8(rdB, wdB, accB);
    }
    for (; i < s1; i++) {
        int sa = *(const int*)(cc + (unsigned)i * 4u);
        unsigned oa = ((unsigned)sa) << 8;
        unsigned ea4 = (((unsigned)sa) << 4) + ho;
        uint4 raA = *(const uint4*)(hpA + oa + jo);
        uint4 raB = *(const uint4*)(hpB + oa + jo);
        float eaA = *(const float*)(epA + ea4) + ednA;
        float eaB = *(const float*)(epB + ea4) + ednB;
        eaA = (eaA >= 0.f) ? eaA : cLEAKY * eaA;
        eaB = (eaB >= 0.f) ? eaB : cLEAKY * eaB;
        float waA = __builtin_amdgcn_exp2f(eaA);
        float waB = __builtin_amdgcn_exp2f(eaB);
        denA += waA; denB += waB;
        fma8(raA, waA, accA);
        fma8(raB, waB, accB);
    }
    finish8(accA, denA, bias, j, rA);
    finish8(accB, denB, bias, j, rB);
}

// ---------------- fused agg(layer1, 2 planes) + GEMM2 + scores2 ----------------
// block = (tpair, 16 contiguous nodes) covering planes t and t+4.
__global__ __launch_bounds__(256) void agg_gemm_kernel(
        const unsigned short* __restrict__ hb, const float* __restrict__ es,
        const float* __restrict__ ed, const int* __restrict__ offs,
        const int* __restrict__ csr, const float* __restrict__ bias,
        const unsigned short* __restrict__ W2, const float* __restrict__ a_src,
        const float* __restrict__ a_dst, unsigned short* __restrict__ hb2,
        float* __restrict__ es2, float* __restrict__ ed2) {
    __shared__ unsigned short tile[2][16 * 128];   // XOR-swizzled bf16 x2 tiles
    __shared__ float hl[2][16][132];
    int b    = blockIdx.x;
    int tp   = b & 3;
    int g    = b >> 2;
    int tA   = tp, tB = tp + 4;
    int tid  = threadIdx.x;
    int lrow = tid >> 4;
    int j    = tid & 15;
    int n0   = g * 16;
    int n    = n0 + lrow;

    float rA[8], rB[8];
    agg_core2(hb, es, ed, offs, csr, bias, tA, tB, n, j, rA, rB);
    unsigned tb = (unsigned)lrow * 256u + (((unsigned)j * 16u) ^ (((unsigned)(lrow & 7)) << 4));
    {
        uint4 o;
        o.x = pack2(rA[0], rA[1]); o.y = pack2(rA[2], rA[3]);
        o.z = pack2(rA[4], rA[5]); o.w = pack2(rA[6], rA[7]);
        *(uint4*)((char*)tile[0] + tb) = o;
    }
    {
        uint4 o;
        o.x = pack2(rB[0], rB[1]); o.y = pack2(rB[2], rB[3]);
        o.z = pack2(rB[4], rB[5]); o.w = pack2(rB[6], rB[7]);
        *(uint4*)((char*)tile[1] + tb) = o;
    }
    __syncthreads();

    // ---- in-block GEMM for both planes; W2 fragment loaded once ----
    int wave = tid >> 6;
    int lane = tid & 63;
    int q    = lane >> 4;
    int mi   = lane & 15;
    bf16x8 afA[4], afB[4];
    #pragma unroll
    for (int s = 0; s < 4; s++) {
        unsigned addr = (unsigned)mi * 256u +
                        (((unsigned)(s * 64 + q * 16)) ^ (((unsigned)(mi & 7)) << 4));
        afA[s] = *(const bf16x8*)((const char*)tile[0] + addr);
        afB[s] = *(const bf16x8*)((const char*)tile[1] + addr);
    }
    f32x4 aA[2], aB[2];
    aA[0] = (f32x4){0.f, 0.f, 0.f, 0.f}; aA[1] = aA[0];
    aB[0] = aA[0]; aB[1] = aA[0];
    #pragma unroll
    for (int ct = 0; ct < 2; ct++) {
        int c = (wave * 2 + ct) * 16 + mi;
        #pragma unroll
        for (int s = 0; s < 4; s++) {
            bf16x8 bfrag = *(const bf16x8*)(W2 + (size_t)c * cHID + s * 32 + q * 8);
            aA[ct] = __builtin_amdgcn_mfma_f32_16x16x32_bf16(afA[s], bfrag, aA[ct], 0, 0, 0);
            aB[ct] = __builtin_amdgcn_mfma_f32_16x16x32_bf16(afB[s], bfrag, aB[ct], 0, 0, 0);
        }
    }
    #pragma unroll
    for (int ct = 0; ct < 2; ct++)
        #pragma unroll
        for (int rr = 0; rr < 4; rr++) {
            hl[0][q * 4 + rr][(wave * 2 + ct) * 16 + mi] = aA[ct][rr];
            hl[1][q * 4 + rr][(wave * 2 + ct) * 16 + mi] = aB[ct][rr];
        }
    __syncthreads();

    if (tid < 128) {   // 2 planes x 16 rows x 4 heads
        int p  = tid >> 6;
        int r2 = tid & 15;
        int hd = (tid >> 4) & 3;
        int tcur = p ? tB : tA;
        int rg = tcur * cN + n0 + r2;
        const float* hr = &hl[p][r2][hd * cF];
        const float* sa = a_src + hd * cF;
        const float* da = a_dst + hd * cF;
        float s1 = 0.f, s2 = 0.f;
        #pragma unroll 8
        for (int f = 0; f < cF; f++) {
            float hv = hr[f];
            s1 += hv * sa[f];
            s2 += hv * da[f];
        }
        es2[(size_t)rg * cHEADS + hd] = s1 * cL2E;
        ed2[(size_t)rg * cHEADS + hd] = s2 * cL2E;
    }
    #pragma unroll
    for (int p = 0; p < 2; p++) {
        int row = tid >> 4;
        int c8  = (tid & 15) * 8;
        int tcur = p ? tB : tA;
        float4 v0 = *(const float4*)&hl[p][row][c8];
        float4 v1 = *(const float4*)&hl[p][row][c8 + 4];
        uint4 o;
        o.x = pack2(v0.x, v0.y); o.y = pack2(v0.z, v0.w);
        o.z = pack2(v1.x, v1.y); o.w = pack2(v1.z, v1.w);
        *(uint4*)(hb2 + (size_t)(tcur * cN + n0 + row) * cHID + c8) = o;
    }
}

// ---------------- fused agg(layer2, 2 planes) + MLP head -> out ----------------
__global__ __launch_bounds__(256) void TemporalGAT_20005957665499_kernel(
        const unsigned short* __restrict__ hb2, const float* __restrict__ es,
        const float* __restrict__ ed, const int* __restrict__ offs,
        const int* __restrict__ csr, const float* __restrict__ bias,
        const unsigned short* __restrict__ lw1b, const float* __restrict__ lb1,
        const float* __restrict__ lw2, const float* __restrict__ lb2,
        float* __restrict__ out) {
    __shared__ unsigned short tile[2][16 * 128];
    int b    = blockIdx.x;
    int tp   = b & 3;
    int g    = b >> 2;
    int tA   = tp, tB = tp + 4;
    int tid  = threadIdx.x;
    int lrow = tid >> 4;
    int j    = tid & 15;
    int n0   = g * 16;
    int n    = n0 + lrow;

    float rA[8], rB[8];
    agg_core2(hb2, es, ed, offs, csr, bias, tA, tB, n, j, rA, rB);
    unsigned tb = (unsigned)lrow * 256u + (((unsigned)j * 16u) ^ (((unsigned)(lrow & 7)) << 4));
    {
        uint4 o;
        o.x = pack2(rA[0], rA[1]); o.y = pack2(rA[2], rA[3]);
        o.z = pack2(rA[4], rA[5]); o.w = pack2(rA[6], rA[7]);
        *(uint4*)((char*)tile[0] + tb) = o;
    }
    {
        uint4 o;
        o.x = pack2(rB[0], rB[1]); o.y = pack2(rB[2], rB[3]);
        o.z = pack2(rB[4], rB[5]); o.w = pack2(rB[6], rB[7]);
        *(uint4*)((char*)tile[1] + tb) = o;
    }
    __syncthreads();

    int wave = tid >> 6;
    if (wave < 2) {      // wave p: 16x128 @ 128x32 MLP for plane p, dot with lw2
        int p  = wave;
        int t  = p ? tB : tA;
        int lane = tid & 63;
        int q  = lane >> 4;
        int mi = lane & 15;
        bf16x8 afrag[4];
        #pragma unroll
        for (int s = 0; s < 4; s++) {
            unsigned addr = (unsigned)mi * 256u +
                            (((unsigned)(s * 64 + q * 16)) ^ (((unsigned)(mi & 7)) << 4));
            afrag[s] = *(const bf16x8*)((const char*)tile[p] + addr);
        }
        f32x4 acc2[2];
        acc2[0] = (f32x4){0.f, 0.f, 0.f, 0.f};
        acc2[1] = acc2[0];
        #pragma unroll
        for (int ct = 0; ct < 2; ct++) {
            int c = ct * 16 + mi;
            #pragma unroll
            for (int s = 0; s < 4; s++) {
                bf16x8 bfrag = *(const bf16x8*)(lw1b + (size_t)c * cHID + s * 32 + q * 8);
                acc2[ct] = __builtin_amdgcn_mfma_f32_16x16x32_bf16(afrag[s], bfrag, acc2[ct], 0, 0, 0);
            }
        }
        float lb1a = lb1[mi], lb1b_ = lb1[16 + mi];
        float lw2a = lw2[mi], lw2b_ = lw2[16 + mi];
        float l2 = lb2[0];
        #pragma unroll
        for (int rr = 0; rr < 4; rr++) {
            float va = fmaxf(acc2[0][rr] + lb1a, 0.f);
            float vb = fmaxf(acc2[1][rr] + lb1b_, 0.f);
            float v = va * lw2a + vb * lw2b_;
            v += __shfl_xor(v, 1);
            v += __shfl_xor(v, 2);
            v += __shfl_xor(v, 4);
            v += __shfl_xor(v, 8);
            if (mi == 0) out[t * cN + n0 + q * 4 + rr] = v + l2;
        }
    }
}

// ---------------- launch ----------------
extern "C" void kernel_launch(void* const* d_in, const int* in_sizes, int n_in,
                              void* d_out, int out_size, void* d_ws, size_t ws_size,
                              hipStream_t stream) {
    const float* x   = (const float*)d_in[0];   // [N,T,64] fp32
    const int*   ei  = (const int*)d_in[1];
    const float* W1  = (const float*)d_in[2];
    const float* as1 = (const float*)d_in[3];
    const float* ad1 = (const float*)d_in[4];
    const float* b1  = (const float*)d_in[5];
    const float* W2  = (const float*)d_in[6];
    const float* as2 = (const float*)d_in[7];
    const float* ad2 = (const float*)d_in[8];
    const float* b2  = (const float*)d_in[9];
    const float* lw1 = (const float*)d_in[10];
    const float* lb1 = (const float*)d_in[11];
    const float* lw2 = (const float*)d_in[12];
    const float* lb2 = (const float*)d_in[13];
    float* out = (float*)d_out;                 // [T,N,1] fp32 == rho-major
    (void)in_sizes; (void)n_in; (void)out_size; (void)ws_size;

    // workspace carve, 256B-aligned
    char* ws = (char*)d_ws;
    size_t o = 0;
    auto carveN = [&](size_t bytes) { void* p = ws + o; o += (bytes + 255) & ~(size_t)255; return p; };
    unsigned short* hb   = (unsigned short*)carveN((size_t)cR * cHID * 2);    // 41 MB (layer-1 h)
    unsigned short* hb2  = (unsigned short*)carveN((size_t)cR * cHID * 2);    // 41 MB (layer-2 h)
    unsigned short* W1b  = (unsigned short*)carveN((size_t)cHID * cFIN * 2);
    unsigned short* W2b  = (unsigned short*)carveN((size_t)cHID * cHID * 2);
    unsigned short* lw1b = (unsigned short*)carveN((size_t)cF * cHID * 2);
    float* es1_buf = (float*)carveN((size_t)cR * cHEADS * 4);                 // 2.6 MB each
    float* ed1_buf = (float*)carveN((size_t)cR * cHEADS * 4);
    float* es2_buf = (float*)carveN((size_t)cR * cHEADS * 4);
    float* ed2_buf = (float*)carveN((size_t)cR * cHEADS * 4);
    int*   deg     = (int*)carveN((size_t)cN * 4);
    int*   offs    = (int*)carveN((size_t)(cN + 1) * 4);
    int*   cursor  = (int*)carveN((size_t)cN * 4);
    int*   csr     = (int*)carveN((size_t)cET * 4);

    // ---- weight conversion + degree count (fused), CSR build ----
    hipMemsetAsync(deg, 0, (size_t)cN * 4, stream);
    cvt_deg_kernel<<<(cE + 255) / 256, 256, 0, stream>>>(W1, W2, lw1, ei, W1b, W2b, lw1b, deg);
    scan_kernel<<<1, 256, 0, stream>>>(deg, offs, cursor);
    scatter_kernel<<<(cET + 255) / 256, 256, 0, stream>>>(ei, cursor, csr);

    // ---- layer 1 GEMM (x read + cvt fused) ----
    gemm1_fused_kernel<<<cR / 64, 256, 0, stream>>>(x, W1b, as1, ad1, hb, es1_buf, ed1_buf);
    // ---- agg1 + GEMM2 + scores2 (fused, 2 t-planes per block) ----
    agg_gemm_kernel<<<(cN / 16) * (cT / 2), 256, 0, stream>>>(
        hb, es1_buf, ed1_buf, offs, csr, b1, W2b, as2, ad2, hb2, es2_buf, ed2_buf);
    // ---- agg2 + MLP head (fused, 2 t-planes per block) -> out ----
    TemporalGAT_20005957665499_kernel<<<(cN / 16) * (cT / 2), 256, 0, stream>>>(
        hb2, es2_buf, ed2_buf, offs, csr, b2, lw1b, lb1, lw2, lb2, out);
}

// Round 5
// 414.218 us; speedup vs baseline: 1.0566x; 1.0566x over previous
//
#include <hip/hip_runtime.h>

// ---------------- problem constants ----------------
constexpr int cN     = 20000;
constexpr int cT     = 8;
constexpr int cFIN   = 64;
constexpr int cHEADS = 4;
constexpr int cF     = 32;
constexpr int cHID   = 128;        // cHEADS * cF
constexpr int cE     = 320000;
constexpr int cET    = cE + cN;    // edges + self loops
constexpr int cR     = cN * cT;    // 160000 batched rows, rho = t*N + n (t-major)
constexpr float cLEAKY = 0.2f;
constexpr float cL2E = 1.44269504088896340736f;   // log2(e)

typedef __attribute__((ext_vector_type(8))) short bf16x8;   // MFMA A/B frag
typedef __attribute__((ext_vector_type(4))) float f32x4;    // MFMA C/D frag
typedef __attribute__((ext_vector_type(2))) float f32x2;    // packed fp32 (v_pk_*)

static __device__ __forceinline__ unsigned short f2bfu(float f) {
    unsigned int u;
    __builtin_memcpy(&u, &f, 4);
    u += 0x7FFFu + ((u >> 16) & 1u);
    return (unsigned short)(u >> 16);
}
static __device__ __forceinline__ f32x2 bfp2(unsigned int v) {
    unsigned int ul = v << 16, uh = v & 0xFFFF0000u;
    float lo, hi;
    __builtin_memcpy(&lo, &ul, 4);
    __builtin_memcpy(&hi, &uh, 4);
    return (f32x2){lo, hi};
}
static __device__ __forceinline__ unsigned int pack2(float lo, float hi) {
    unsigned int ul, uh;
    __builtin_memcpy(&ul, &lo, 4);
    __builtin_memcpy(&uh, &hi, 4);
    ul += 0x7FFFu + ((ul >> 16) & 1u);
    uh += 0x7FFFu + ((uh >> 16) & 1u);
    return (ul >> 16) | (uh & 0xFFFF0000u);
}
// 16 features from two uint4 (32B), packed fp32 accumulate
static __device__ __forceinline__ void fma16(uint4 r0, uint4 r1, float w, f32x2* acc) {
    f32x2 w2 = (f32x2){w, w};
    acc[0] += w2 * bfp2(r0.x); acc[1] += w2 * bfp2(r0.y);
    acc[2] += w2 * bfp2(r0.z); acc[3] += w2 * bfp2(r0.w);
    acc[4] += w2 * bfp2(r1.x); acc[5] += w2 * bfp2(r1.y);
    acc[6] += w2 * bfp2(r1.z); acc[7] += w2 * bfp2(r1.w);
}

// ---------------- fused weight conversion + degree count ----------------
__global__ void cvt_deg_kernel(const float* W1, const float* W2, const float* lw1,
                               const int* ei, unsigned short* W1b, unsigned short* W2b,
                               unsigned short* lw1b, int* deg) {
    int i = blockIdx.x * 256 + threadIdx.x;
    if (i < cHID * cFIN)                      W1b[i] = f2bfu(W1[i]);
    else if (i < cHID * cFIN + cHID * cHID)   W2b[i - cHID * cFIN] = f2bfu(W2[i - cHID * cFIN]);
    else if (i < cHID * cFIN + cHID * cHID + cF * cHID)
        lw1b[i - cHID * cFIN - cHID * cHID] = f2bfu(lw1[i - cHID * cFIN - cHID * cHID]);
    if (i < cE) atomicAdd(&deg[ei[cE + i]], 1);
}

// LDS-staged scan; self-loop (+1) folded into the read.
__global__ void scan_kernel(const int* deg, int* offs, int* cur) {
    __shared__ int sdeg[79 * 256];     // 20224 >= cN
    __shared__ int lds[256];
    int tid = threadIdx.x;
    #pragma unroll 4
    for (int k = 0; k < 79; k++) {
        int idx = k * 256 + tid;
        sdeg[idx] = (idx < cN) ? deg[idx] + 1 : 0;
    }
    __syncthreads();
    const int CH = 79;
    int base = tid * CH;
    int tot = 0;
    #pragma unroll 8
    for (int j = 0; j < CH; j++) tot += sdeg[base + j];
    lds[tid] = tot;
    __syncthreads();
    for (int off = 1; off < 256; off <<= 1) {
        int v = (tid >= off) ? lds[tid - off] : 0;
        __syncthreads();
        lds[tid] += v;
        __syncthreads();
    }
    int run = lds[tid] - tot;
    for (int j = 0; j < CH; j++) {
        int idx = base + j;
        if (idx < cN) { offs[idx] = run; cur[idx] = run; run += sdeg[idx]; }
    }
    if (tid == 255) offs[cN] = lds[255];
}
__global__ void scatter_kernel(const int* ei, int* cur, int* csr) {
    int e = blockIdx.x * blockDim.x + threadIdx.x;
    if (e >= cET) return;
    int s, d;
    if (e < cE) { s = ei[e]; d = ei[cE + e]; }
    else        { s = e - cE; d = s; }
    int pos = atomicAdd(&cur[d], 1);
    csr[pos] = s;
}

// ---------------- GEMM1 (fused fp32->bf16 cvt of x) + scores ----------------
__global__ __launch_bounds__(256) void gemm1_fused_kernel(
        const float* __restrict__ x, const unsigned short* __restrict__ W,
        const float* __restrict__ a_src, const float* __restrict__ a_dst,
        unsigned short* __restrict__ hb, float* __restrict__ es, float* __restrict__ ed) {
    __shared__ float hl[64][132];
    int tid  = threadIdx.x;
    int wave = tid >> 6;
    int lane = tid & 63;
    int q    = lane >> 4;
    int mi   = lane & 15;
    int m0   = blockIdx.x * 64 + wave * 16;

    int rho = m0 + mi;
    int t = rho / cN;
    int n = rho - t * cN;
    const float* xr = x + (size_t)n * (cT * cFIN) + t * cFIN;

    bf16x8 afrag[2];
    #pragma unroll
    for (int s = 0; s < 2; s++) {
        float4 v0 = *(const float4*)(xr + s * 32 + q * 8);
        float4 v1 = *(const float4*)(xr + s * 32 + q * 8 + 4);
        bf16x8 f;
        f[0] = (short)f2bfu(v0.x); f[1] = (short)f2bfu(v0.y);
        f[2] = (short)f2bfu(v0.z); f[3] = (short)f2bfu(v0.w);
        f[4] = (short)f2bfu(v1.x); f[5] = (short)f2bfu(v1.y);
        f[6] = (short)f2bfu(v1.z); f[7] = (short)f2bfu(v1.w);
        afrag[s] = f;
    }

    f32x4 acc[8];
    #pragma unroll
    for (int ct = 0; ct < 8; ct++) acc[ct] = (f32x4){0.f, 0.f, 0.f, 0.f};
    #pragma unroll
    for (int ct = 0; ct < 8; ct++) {
        int c = ct * 16 + mi;
        #pragma unroll
        for (int s = 0; s < 2; s++) {
            bf16x8 bfrag = *(const bf16x8*)(W + (size_t)c * cFIN + s * 32 + q * 8);
            acc[ct] = __builtin_amdgcn_mfma_f32_16x16x32_bf16(afrag[s], bfrag, acc[ct], 0, 0, 0);
        }
    }

    #pragma unroll
    for (int ct = 0; ct < 8; ct++)
        #pragma unroll
        for (int r = 0; r < 4; r++)
            hl[wave * 16 + q * 4 + r][ct * 16 + mi] = acc[ct][r];
    __syncthreads();

    {
        int r2 = tid & 63;
        int hd = tid >> 6;
        int rg = blockIdx.x * 64 + r2;
        const float* hr = &hl[r2][hd * cF];
        const float* sa = a_src + hd * cF;
        const float* da = a_dst + hd * cF;
        float s1 = 0.f, s2 = 0.f;
        #pragma unroll 8
        for (int f = 0; f < cF; f++) {
            float hv = hr[f];
            s1 += hv * sa[f];
            s2 += hv * da[f];
        }
        es[rg * cHEADS + hd] = s1 * cL2E;
        ed[rg * cHEADS + hd] = s2 * cL2E;
    }

    size_t base = (size_t)blockIdx.x * 64 * cHID;
    #pragma unroll
    for (int it = 0; it < 8; it++) {
        int g   = tid + it * 256;
        int row = g >> 5;
        int c4  = (g & 31) * 4;
        float4 v = *(const float4*)&hl[row][c4];
        unsigned int p0 = pack2(v.x, v.y), p1 = pack2(v.z, v.w);
        *(uint2*)(hb + base + (size_t)row * cHID + c4) = make_uint2(p0, p1);
    }
}

// ---------------- agg core: one (row, 16-feature slice) per thread ----------------
// 8 lanes/row x 16 feats/lane: halves per-edge metadata replication vs 16x8.
// Scores pre-scaled by log2(e); w = exp2(leaky(es+ed)). Packed f32 fma.
static __device__ __forceinline__ void agg_core16(
        const unsigned short* __restrict__ hb, const float* __restrict__ es,
        const float* __restrict__ ed, const int* __restrict__ offs,
        const int* __restrict__ csr, const float* __restrict__ bias,
        int t, int n, int j, float* r) {
    int head = j >> 1;
    int s0 = offs[n], s1 = offs[n + 1];
    float edn = ed[(size_t)(t * cN + n) * cHEADS + head];
    const char* hp = (const char*)(hb + (size_t)t * cN * cHID);
    const char* ep = (const char*)(es + (size_t)t * cN * cHEADS);
    const char* cc = (const char*)csr;
    unsigned jo = (unsigned)j * 32u;
    unsigned ho = (unsigned)head * 4u;

    f32x2 acc[8];
    #pragma unroll
    for (int k = 0; k < 8; k++) acc[k] = (f32x2){0.f, 0.f};
    float den = 0.f;
    int i = s0;
    for (; i + 1 < s1; i += 2) {
        unsigned io = (unsigned)i * 4u;
        int sa = *(const int*)(cc + io);
        int sb = *(const int*)(cc + io + 4u);
        unsigned oa = ((unsigned)sa) << 8, ob = ((unsigned)sb) << 8;
        uint4 ra0 = *(const uint4*)(hp + oa + jo);
        uint4 ra1 = *(const uint4*)(hp + oa + jo + 16u);
        uint4 rb0 = *(const uint4*)(hp + ob + jo);
        uint4 rb1 = *(const uint4*)(hp + ob + jo + 16u);
        float ea = *(const float*)(ep + (((unsigned)sa) << 4) + ho) + edn;
        float eb = *(const float*)(ep + (((unsigned)sb) << 4) + ho) + edn;
        ea = (ea >= 0.f) ? ea : cLEAKY * ea;
        eb = (eb >= 0.f) ? eb : cLEAKY * eb;
        float wa = __builtin_amdgcn_exp2f(ea);
        float wb = __builtin_amdgcn_exp2f(eb);
        den += wa; den += wb;
        fma16(ra0, ra1, wa, acc);
        fma16(rb0, rb1, wb, acc);
    }
    for (; i < s1; i++) {
        int sa = *(const int*)(cc + (unsigned)i * 4u);
        unsigned oa = ((unsigned)sa) << 8;
        uint4 ra0 = *(const uint4*)(hp + oa + jo);
        uint4 ra1 = *(const uint4*)(hp + oa + jo + 16u);
        float ea = *(const float*)(ep + (((unsigned)sa) << 4) + ho) + edn;
        ea = (ea >= 0.f) ? ea : cLEAKY * ea;
        float wa = __builtin_amdgcn_exp2f(ea);
        den += wa;
        fma16(ra0, ra1, wa, acc);
    }
    float inv = 1.f / (den + 1e-16f);
    const float* bp = bias + 16 * j;
    #pragma unroll
    for (int k = 0; k < 8; k++) {
        float v0 = acc[k].x * inv + bp[2 * k];
        float v1 = acc[k].y * inv + bp[2 * k + 1];
        r[2 * k]     = (v0 > 0.f) ? v0 : expm1f(v0);
        r[2 * k + 1] = (v1 > 0.f) ? v1 : expm1f(v1);
    }
}

// writes the 16-feature result to the XOR-swizzled bf16 tile
static __device__ __forceinline__ void tile_write16(unsigned short* tile, int row, int j,
                                                    const float* r) {
    uint4 o0, o1;
    o0.x = pack2(r[0], r[1]);  o0.y = pack2(r[2], r[3]);
    o0.z = pack2(r[4], r[5]);  o0.w = pack2(r[6], r[7]);
    o1.x = pack2(r[8], r[9]);  o1.y = pack2(r[10], r[11]);
    o1.z = pack2(r[12], r[13]); o1.w = pack2(r[14], r[15]);
    unsigned swz = ((unsigned)(row & 7)) << 4;
    unsigned jo  = (unsigned)j * 32u;
    char* base = (char*)tile + (unsigned)row * 256u;
    *(uint4*)(base + (jo ^ swz)) = o0;
    *(uint4*)(base + ((jo + 16u) ^ swz)) = o1;
}

// ---------------- fused agg(layer1) + GEMM2 + scores2 ----------------
// block = (t, 32 contiguous nodes): t = b&7 keeps the per-XCD single-plane
// L2 affinity (round-4 lesson). 8 lanes/row agg -> two 16x128 tiles -> MFMA.
__global__ __launch_bounds__(256) void agg_gemm_kernel(
        const unsigned short* __restrict__ hb, const float* __restrict__ es,
        const float* __restrict__ ed, const int* __restrict__ offs,
        const int* __restrict__ csr, const float* __restrict__ bias,
        const unsigned short* __restrict__ W2, const float* __restrict__ a_src,
        const float* __restrict__ a_dst, unsigned short* __restrict__ hb2,
        float* __restrict__ es2, float* __restrict__ ed2) {
    __shared__ unsigned short tile[32 * 128];   // 8 KB, XOR-swizzled rows
    __shared__ float hl[2][16][132];
    int b    = blockIdx.x;
    int t    = b & 7;
    int g    = b >> 3;
    int tid  = threadIdx.x;
    int row  = tid >> 3;        // 0..31
    int j    = tid & 7;         // 16-feature slice
    int n0   = g * 32;
    int n    = n0 + row;

    float r[16];
    agg_core16(hb, es, ed, offs, csr, bias, t, n, j, r);
    tile_write16(tile, row, j, r);
    __syncthreads();

    // ---- in-block GEMM: h2 = x2 @ W2^T (K=128), two 16-row tiles ----
    int wave = tid >> 6;
    int lane = tid & 63;
    int q    = lane >> 4;
    int mi   = lane & 15;
    int p    = wave >> 1;       // tile (row block)
    int ch   = wave & 1;        // column half (4 ct each)
    bf16x8 afrag[4];
    #pragma unroll
    for (int s = 0; s < 4; s++) {
        unsigned addr = (unsigned)(p * 16 + mi) * 256u +
                        (((unsigned)(s * 64 + q * 16)) ^ (((unsigned)(mi & 7)) << 4));
        afrag[s] = *(const bf16x8*)((const char*)tile + addr);
    }
    f32x4 acc2[4];
    #pragma unroll
    for (int ct = 0; ct < 4; ct++) acc2[ct] = (f32x4){0.f, 0.f, 0.f, 0.f};
    #pragma unroll
    for (int ct = 0; ct < 4; ct++) {
        int c = (ch * 4 + ct) * 16 + mi;
        #pragma unroll
        for (int s = 0; s < 4; s++) {
            bf16x8 bfrag = *(const bf16x8*)(W2 + (size_t)c * cHID + s * 32 + q * 8);
            acc2[ct] = __builtin_amdgcn_mfma_f32_16x16x32_bf16(afrag[s], bfrag, acc2[ct], 0, 0, 0);
        }
    }
    #pragma unroll
    for (int ct = 0; ct < 4; ct++)
        #pragma unroll
        for (int rr = 0; rr < 4; rr++)
            hl[p][q * 4 + rr][(ch * 4 + ct) * 16 + mi] = acc2[ct][rr];
    __syncthreads();

    if (tid < 128) {   // 2 tiles x 16 rows x 4 heads scores
        int pp = tid >> 6;
        int r2 = tid & 15;
        int hd = (tid >> 4) & 3;
        int rg = t * cN + n0 + pp * 16 + r2;
        const float* hr = &hl[pp][r2][hd * cF];
        const float* sa = a_src + hd * cF;
        const float* da = a_dst + hd * cF;
        float s1 = 0.f, s2 = 0.f;
        #pragma unroll 8
        for (int f = 0; f < cF; f++) {
            float hv = hr[f];
            s1 += hv * sa[f];
            s2 += hv * da[f];
        }
        es2[(size_t)rg * cHEADS + hd] = s1 * cL2E;
        ed2[(size_t)rg * cHEADS + hd] = s2 * cL2E;
    }
    #pragma unroll
    for (int pp = 0; pp < 2; pp++) {
        int rw = tid >> 4;
        int c8 = (tid & 15) * 8;
        float4 v0 = *(const float4*)&hl[pp][rw][c8];
        float4 v1 = *(const float4*)&hl[pp][rw][c8 + 4];
        uint4 o;
        o.x = pack2(v0.x, v0.y); o.y = pack2(v0.z, v0.w);
        o.z = pack2(v1.x, v1.y); o.w = pack2(v1.z, v1.w);
        *(uint4*)(hb2 + (size_t)(t * cN + n0 + pp * 16 + rw) * cHID + c8) = o;
    }
}

// ---------------- fused agg(layer2) + MLP head -> out ----------------
__global__ __launch_bounds__(256) void TemporalGAT_20005957665499_kernel(
        const unsigned short* __restrict__ hb2, const float* __restrict__ es,
        const float* __restrict__ ed, const int* __restrict__ offs,
        const int* __restrict__ csr, const float* __restrict__ bias,
        const unsigned short* __restrict__ lw1b, const float* __restrict__ lb1,
        const float* __restrict__ lw2, const float* __restrict__ lb2,
        float* __restrict__ out) {
    __shared__ unsigned short tile[32 * 128];
    int b    = blockIdx.x;
    int t    = b & 7;
    int g    = b >> 3;
    int tid  = threadIdx.x;
    int row  = tid >> 3;
    int j    = tid & 7;
    int n0   = g * 32;
    int n    = n0 + row;

    float r[16];
    agg_core16(hb2, es, ed, offs, csr, bias, t, n, j, r);
    tile_write16(tile, row, j, r);
    __syncthreads();

    int wave = tid >> 6;
    if (wave < 2) {      // wave p: rows 16p..16p+15: 16x128 @ 128x32 MLP + lw2 dot
        int p  = wave;
        int lane = tid & 63;
        int q  = lane >> 4;
        int mi = lane & 15;
        bf16x8 afrag[4];
        #pragma unroll
        for (int s = 0; s < 4; s++) {
            unsigned addr = (unsigned)(p * 16 + mi) * 256u +
                            (((unsigned)(s * 64 + q * 16)) ^ (((unsigned)(mi & 7)) << 4));
            afrag[s] = *(const bf16x8*)((const char*)tile + addr);
        }
        f32x4 acc2[2];
        acc2[0] = (f32x4){0.f, 0.f, 0.f, 0.f};
        acc2[1] = acc2[0];
        #pragma unroll
        for (int ct = 0; ct < 2; ct++) {
            int c = ct * 16 + mi;
            #pragma unroll
            for (int s = 0; s < 4; s++) {
                bf16x8 bfrag = *(const bf16x8*)(lw1b + (size_t)c * cHID + s * 32 + q * 8);
                acc2[ct] = __builtin_amdgcn_mfma_f32_16x16x32_bf16(afrag[s], bfrag, acc2[ct], 0, 0, 0);
            }
        }
        float lb1a = lb1[mi], lb1b_ = lb1[16 + mi];
        float lw2a = lw2[mi], lw2b_ = lw2[16 + mi];
        float l2 = lb2[0];
        #pragma unroll
        for (int rr = 0; rr < 4; rr++) {
            float va = fmaxf(acc2[0][rr] + lb1a, 0.f);
            float vb = fmaxf(acc2[1][rr] + lb1b_, 0.f);
            float v = va * lw2a + vb * lw2b_;
            v += __shfl_xor(v, 1);
            v += __shfl_xor(v, 2);
            v += __shfl_xor(v, 4);
            v += __shfl_xor(v, 8);
            if (mi == 0) out[t * cN + n0 + p * 16 + q * 4 + rr] = v + l2;
        }
    }
}

// ---------------- launch ----------------
extern "C" void kernel_launch(void* const* d_in, const int* in_sizes, int n_in,
                              void* d_out, int out_size, void* d_ws, size_t ws_size,
                              hipStream_t stream) {
    const float* x   = (const float*)d_in[0];   // [N,T,64] fp32
    const int*   ei  = (const int*)d_in[1];
    const float* W1  = (const float*)d_in[2];
    const float* as1 = (const float*)d_in[3];
    const float* ad1 = (const float*)d_in[4];
    const float* b1  = (const float*)d_in[5];
    const float* W2  = (const float*)d_in[6];
    const float* as2 = (const float*)d_in[7];
    const float* ad2 = (const float*)d_in[8];
    const float* b2  = (const float*)d_in[9];
    const float* lw1 = (const float*)d_in[10];
    const float* lb1 = (const float*)d_in[11];
    const float* lw2 = (const float*)d_in[12];
    const float* lb2 = (const float*)d_in[13];
    float* out = (float*)d_out;                 // [T,N,1] fp32 == rho-major
    (void)in_sizes; (void)n_in; (void)out_size; (void)ws_size;

    // workspace carve, 256B-aligned
    char* ws = (char*)d_ws;
    size_t o = 0;
    auto carveN = [&](size_t bytes) { void* p = ws + o; o += (bytes + 255) & ~(size_t)255; return p; };
    unsigned short* hb   = (unsigned short*)carveN((size_t)cR * cHID * 2);    // 41 MB (layer-1 h)
    unsigned short* hb2  = (unsigned short*)carveN((size_t)cR * cHID * 2);    // 41 MB (layer-2 h)
    unsigned short* W1b  = (unsigned short*)carveN((size_t)cHID * cFIN * 2);
    unsigned short* W2b  = (unsigned short*)carveN((size_t)cHID * cHID * 2);
    unsigned short* lw1b = (unsigned short*)carveN((size_t)cF * cHID * 2);
    float* es1_buf = (float*)carveN((size_t)cR * cHEADS * 4);                 // 2.6 MB each
    float* ed1_buf = (float*)carveN((size_t)cR * cHEADS * 4);
    float* es2_buf = (float*)carveN((size_t)cR * cHEADS * 4);
    float* ed2_buf = (float*)carveN((size_t)cR * cHEADS * 4);
    int*   deg     = (int*)carveN((size_t)cN * 4);
    int*   offs    = (int*)carveN((size_t)(cN + 1) * 4);
    int*   cursor  = (int*)carveN((size_t)cN * 4);
    int*   csr     = (int*)carveN((size_t)cET * 4);

    // ---- weight conversion + degree count (fused), CSR build ----
    hipMemsetAsync(deg, 0, (size_t)cN * 4, stream);
    cvt_deg_kernel<<<(cE + 255) / 256, 256, 0, stream>>>(W1, W2, lw1, ei, W1b, W2b, lw1b, deg);
    scan_kernel<<<1, 256, 0, stream>>>(deg, offs, cursor);
    scatter_kernel<<<(cET + 255) / 256, 256, 0, stream>>>(ei, cursor, csr);

    // ---- layer 1 GEMM (x read + cvt fused) ----
    gemm1_fused_kernel<<<cR / 64, 256, 0, stream>>>(x, W1b, as1, ad1, hb, es1_buf, ed1_buf);
    // ---- agg1 + GEMM2 + scores2 (fused, 32 nodes/block, t = b&7) ----
    agg_gemm_kernel<<<(cN / 32) * cT, 256, 0, stream>>>(
        hb, es1_buf, ed1_buf, offs, csr, b1, W2b, as2, ad2, hb2, es2_buf, ed2_buf);
    // ---- agg2 + MLP head (fused, 32 nodes/block) -> out ----
    TemporalGAT_20005957665499_kernel<<<(cN / 32) * cT, 256, 0, stream>>>(
        hb2, es2_buf, ed2_buf, offs, csr, b2, lw1b, lb1, lw2, lb2, out);
}

// Round 7
// 387.499 us; speedup vs baseline: 1.1295x; 1.0690x over previous
//
#include <hip/hip_runtime.h>

// ---------------- problem constants ----------------
constexpr int cN     = 20000;
constexpr int cT     = 8;
constexpr int cFIN   = 64;
constexpr int cHEADS = 4;
constexpr int cF     = 32;
constexpr int cHID   = 128;        // cHEADS * cF
constexpr int cE     = 320000;
constexpr int cET    = cE + cN;    // edges + self loops
constexpr int cR     = cN * cT;    // 160000 batched rows, rho = t*N + n (t-major)
constexpr float cLEAKY = 0.2f;
constexpr float cL2E = 1.44269504088896340736f;   // log2(e)

// pi-storage v2 (HEAD-LOCAL): storage dword d = h*16 + mi holds the bf16 pair
// (feature 32h+mi, feature 32h+16+mi). So feat(p) = 32*(p>>5) + ((p>>1)&15) + 16*(p&1).
// Head h occupies contiguous bytes [64h, 64h+64) of each 256B row, so an agg
// lane's 16B slice (dwords 4j..4j+3) is entirely within head j>>2 — the
// single-weight agg_core stays valid (round-6 bug: old pi mixed 4 heads/slice).
// MFMA K-permutation is free as long as A and B agree: W2bP/lw1bP/b1P/b2P are
// permuted once at cvt time; h tiles are written directly from accumulators.

typedef __attribute__((ext_vector_type(8))) short bf16x8;   // MFMA A/B frag
typedef __attribute__((ext_vector_type(4))) float f32x4;    // MFMA C/D frag

static __device__ __forceinline__ unsigned short f2bfu(float f) {
    unsigned int u;
    __builtin_memcpy(&u, &f, 4);
    u += 0x7FFFu + ((u >> 16) & 1u);
    return (unsigned short)(u >> 16);
}
static __device__ __forceinline__ void unpack2(unsigned int v, float& lo, float& hi) {
    unsigned int ul = v << 16, uh = v & 0xFFFF0000u;
    __builtin_memcpy(&lo, &ul, 4);
    __builtin_memcpy(&hi, &uh, 4);
}
static __device__ __forceinline__ unsigned int pack2(float lo, float hi) {
    unsigned int ul, uh;
    __builtin_memcpy(&ul, &lo, 4);
    __builtin_memcpy(&uh, &hi, 4);
    ul += 0x7FFFu + ((ul >> 16) & 1u);
    uh += 0x7FFFu + ((uh >> 16) & 1u);
    return (ul >> 16) | (uh & 0xFFFF0000u);
}
static __device__ __forceinline__ int featOf(int p) {   // pi-v2 storage -> semantic feature
    return ((p >> 5) << 5) + ((p >> 1) & 15) + ((p & 1) << 4);
}

// ---------------- fused weight conversion (pi-v2 permute) + degree count ----------------
__global__ void cvt_deg_kernel(const float* W1, const float* W2, const float* lw1,
                               const float* b1, const float* b2, const int* ei,
                               unsigned short* W1b, unsigned short* W2bP,
                               unsigned short* lw1bP, float* b1P, float* b2P, int* deg) {
    int i = blockIdx.x * 256 + threadIdx.x;
    if (i < 8192) {                                   // W1b plain (K = x-features, linear)
        W1b[i] = f2bfu(W1[i]);
    } else if (i < 8192 + 16384) {                    // W2bP: K permuted to pi-v2 storage
        int jj = i - 8192;
        int c = jj >> 7, p = jj & 127;
        W2bP[jj] = f2bfu(W2[c * cHID + featOf(p)]);
    } else if (i < 8192 + 16384 + 4096) {             // lw1bP: K permuted
        int jj = i - 8192 - 16384;
        int c = jj >> 7, p = jj & 127;
        lw1bP[jj] = f2bfu(lw1[c * cHID + featOf(p)]);
    } else if (i < 8192 + 16384 + 4096 + 128) {       // b1P
        int p = i - 8192 - 16384 - 4096;
        b1P[p] = b1[featOf(p)];
    } else if (i < 8192 + 16384 + 4096 + 256) {       // b2P
        int p = i - 8192 - 16384 - 4096 - 128;
        b2P[p] = b2[featOf(p)];
    }
    if (i < cE) atomicAdd(&deg[ei[cE + i]], 1);
}

// LDS-staged scan; self-loop (+1) folded into the read.
__global__ void scan_kernel(const int* deg, int* offs, int* cur) {
    __shared__ int sdeg[79 * 256];     // 20224 >= cN
    __shared__ int lds[256];
    int tid = threadIdx.x;
    #pragma unroll 4
    for (int k = 0; k < 79; k++) {
        int idx = k * 256 + tid;
        sdeg[idx] = (idx < cN) ? deg[idx] + 1 : 0;
    }
    __syncthreads();
    const int CH = 79;
    int base = tid * CH;
    int tot = 0;
    #pragma unroll 8
    for (int j = 0; j < CH; j++) tot += sdeg[base + j];
    lds[tid] = tot;
    __syncthreads();
    for (int off = 1; off < 256; off <<= 1) {
        int v = (tid >= off) ? lds[tid - off] : 0;
        __syncthreads();
        lds[tid] += v;
        __syncthreads();
    }
    int run = lds[tid] - tot;
    for (int j = 0; j < CH; j++) {
        int idx = base + j;
        if (idx < cN) { offs[idx] = run; cur[idx] = run; run += sdeg[idx]; }
    }
    if (tid == 255) offs[cN] = lds[255];
}
__global__ void scatter_kernel(const int* ei, int* cur, int* csr) {
    int e = blockIdx.x * blockDim.x + threadIdx.x;
    if (e >= cET) return;
    int s, d;
    if (e < cE) { s = ei[e]; d = ei[cE + e]; }
    else        { s = e - cE; d = s; }
    int pos = atomicAdd(&cur[d], 1);
    csr[pos] = s;
}

// ---------------- GEMM1: zero-LDS, direct pi-v2 write, register-shuffle scores ----------------
// Each wave owns an independent 16-row tile (8 ct x 2 k-step MFMA).
// Scores: head h's 32 cols == ct pair (2h,2h+1); partial per lane then
// 4x shfl_xor reduce over the 16-lane mi group. es/ed pre-scaled by log2(e).
__global__ __launch_bounds__(256) void gemm1_fused_kernel(
        const float* __restrict__ x, const unsigned short* __restrict__ W,
        const float* __restrict__ a_src, const float* __restrict__ a_dst,
        unsigned short* __restrict__ hb, float* __restrict__ es, float* __restrict__ ed) {
    int tid  = threadIdx.x;
    int wave = tid >> 6;
    int lane = tid & 63;
    int q    = lane >> 4;
    int mi   = lane & 15;
    int m0   = blockIdx.x * 64 + wave * 16;

    int rho = m0 + mi;
    int t = rho / cN;
    int n = rho - t * cN;
    const float* xr = x + (size_t)n * (cT * cFIN) + t * cFIN;

    bf16x8 afrag[2];
    #pragma unroll
    for (int s = 0; s < 2; s++) {
        float4 v0 = *(const float4*)(xr + s * 32 + q * 8);
        float4 v1 = *(const float4*)(xr + s * 32 + q * 8 + 4);
        bf16x8 f;
        f[0] = (short)f2bfu(v0.x); f[1] = (short)f2bfu(v0.y);
        f[2] = (short)f2bfu(v0.z); f[3] = (short)f2bfu(v0.w);
        f[4] = (short)f2bfu(v1.x); f[5] = (short)f2bfu(v1.y);
        f[6] = (short)f2bfu(v1.z); f[7] = (short)f2bfu(v1.w);
        afrag[s] = f;
    }

    f32x4 acc[8];
    #pragma unroll
    for (int ct = 0; ct < 8; ct++) acc[ct] = (f32x4){0.f, 0.f, 0.f, 0.f};
    #pragma unroll
    for (int ct = 0; ct < 8; ct++) {
        int c = ct * 16 + mi;
        #pragma unroll
        for (int s = 0; s < 2; s++) {
            bf16x8 bfrag = *(const bf16x8*)(W + (size_t)c * cFIN + s * 32 + q * 8);
            acc[ct] = __builtin_amdgcn_mfma_f32_16x16x32_bf16(afrag[s], bfrag, acc[ct], 0, 0, 0);
        }
    }

    // scores from accumulators (fp32, no LDS/barrier)
    #pragma unroll
    for (int h = 0; h < 4; h++) {
        float a0 = a_src[h * 32 + mi], a1 = a_src[h * 32 + 16 + mi];
        float d0 = a_dst[h * 32 + mi], d1 = a_dst[h * 32 + 16 + mi];
        #pragma unroll
        for (int rr = 0; rr < 4; rr++) {
            float vs = acc[2 * h][rr] * a0 + acc[2 * h + 1][rr] * a1;
            float vd = acc[2 * h][rr] * d0 + acc[2 * h + 1][rr] * d1;
            vs += __shfl_xor(vs, 1); vs += __shfl_xor(vs, 2);
            vs += __shfl_xor(vs, 4); vs += __shfl_xor(vs, 8);
            vd += __shfl_xor(vd, 1); vd += __shfl_xor(vd, 2);
            vd += __shfl_xor(vd, 4); vd += __shfl_xor(vd, 8);
            if (mi == 0) {
                int rg = m0 + q * 4 + rr;
                es[rg * cHEADS + h] = vs * cL2E;
                ed[rg * cHEADS + h] = vd * cL2E;
            }
        }
    }

    // direct pi-v2 write: head h's pair (32h+mi, 32h+16+mi) -> dword h*16+mi
    #pragma unroll
    for (int rr = 0; rr < 4; rr++) {
        int rg = m0 + q * 4 + rr;
        unsigned short* hrow = hb + (size_t)rg * cHID;
        #pragma unroll
        for (int h = 0; h < 4; h++) {
            unsigned pv = pack2(acc[2 * h][rr], acc[2 * h + 1][rr]);
            *(unsigned*)(hrow + h * 32 + mi * 2) = pv;
        }
    }
}

// ---------------- agg core: one (row, 8-feature slice) per thread (r1-proven) ----------------
// Slice j = storage bytes [16j,16j+16) == head j>>2 only (pi-v2 head-locality).
// scores es/ed pre-scaled by log2(e); w = exp2(leaky(es+ed)).
static __device__ __forceinline__ void agg_core(
        const unsigned short* __restrict__ hb, const float* __restrict__ es,
        const float* __restrict__ ed, const int* __restrict__ offs,
        const int* __restrict__ csr, const float* __restrict__ bias,
        int t, int n, int j, float* r) {
    int head = j >> 2;
    int rho  = t * cN + n;
    int s0 = offs[n], s1 = offs[n + 1];
    float edn = ed[(size_t)rho * cHEADS + head];
    const char* hpc = (const char*)(hb + (size_t)t * cN * cHID);     // plane base
    const char* epc = (const char*)(es + (size_t)t * cN * cHEADS);
    const char* cc  = (const char*)csr;
    unsigned jo = (unsigned)j * 16u;
    unsigned ho = (unsigned)head * 4u;

    float acc[8] = {};
    float den = 0.f;
    int i = s0;
    for (; i + 3 < s1; i += 4) {
        unsigned io = (unsigned)i * 4u;
        int sa = *(const int*)(cc + io);
        int sb = *(const int*)(cc + io + 4u);
        int sc = *(const int*)(cc + io + 8u);
        int sd = *(const int*)(cc + io + 12u);
        uint4 ra = *(const uint4*)(hpc + (((unsigned)sa) << 8) + jo);
        uint4 rb = *(const uint4*)(hpc + (((unsigned)sb) << 8) + jo);
        uint4 rc = *(const uint4*)(hpc + (((unsigned)sc) << 8) + jo);
        uint4 rd = *(const uint4*)(hpc + (((unsigned)sd) << 8) + jo);
        float ea = *(const float*)(epc + (((unsigned)sa) << 4) + ho) + edn;
        float eb = *(const float*)(epc + (((unsigned)sb) << 4) + ho) + edn;
        float ec = *(const float*)(epc + (((unsigned)sc) << 4) + ho) + edn;
        float ee = *(const float*)(epc + (((unsigned)sd) << 4) + ho) + edn;
        ea = (ea >= 0.f) ? ea : cLEAKY * ea;
        eb = (eb >= 0.f) ? eb : cLEAKY * eb;
        ec = (ec >= 0.f) ? ec : cLEAKY * ec;
        ee = (ee >= 0.f) ? ee : cLEAKY * ee;
        float wa = __builtin_amdgcn_exp2f(ea), wb = __builtin_amdgcn_exp2f(eb);
        float wc = __builtin_amdgcn_exp2f(ec), wd = __builtin_amdgcn_exp2f(ee);
        den += wa; den += wb; den += wc; den += wd;
        float lo, hi;
        unpack2(ra.x, lo, hi); acc[0] += wa * lo; acc[1] += wa * hi;
        unpack2(ra.y, lo, hi); acc[2] += wa * lo; acc[3] += wa * hi;
        unpack2(ra.z, lo, hi); acc[4] += wa * lo; acc[5] += wa * hi;
        unpack2(ra.w, lo, hi); acc[6] += wa * lo; acc[7] += wa * hi;
        unpack2(rb.x, lo, hi); acc[0] += wb * lo; acc[1] += wb * hi;
        unpack2(rb.y, lo, hi); acc[2] += wb * lo; acc[3] += wb * hi;
        unpack2(rb.z, lo, hi); acc[4] += wb * lo; acc[5] += wb * hi;
        unpack2(rb.w, lo, hi); acc[6] += wb * lo; acc[7] += wb * hi;
        unpack2(rc.x, lo, hi); acc[0] += wc * lo; acc[1] += wc * hi;
        unpack2(rc.y, lo, hi); acc[2] += wc * lo; acc[3] += wc * hi;
        unpack2(rc.z, lo, hi); acc[4] += wc * lo; acc[5] += wc * hi;
        unpack2(rc.w, lo, hi); acc[6] += wc * lo; acc[7] += wc * hi;
        unpack2(rd.x, lo, hi); acc[0] += wd * lo; acc[1] += wd * hi;
        unpack2(rd.y, lo, hi); acc[2] += wd * lo; acc[3] += wd * hi;
        unpack2(rd.z, lo, hi); acc[4] += wd * lo; acc[5] += wd * hi;
        unpack2(rd.w, lo, hi); acc[6] += wd * lo; acc[7] += wd * hi;
    }
    for (; i < s1; i++) {
        int sa = *(const int*)(cc + (unsigned)i * 4u);
        uint4 ra = *(const uint4*)(hpc + (((unsigned)sa) << 8) + jo);
        float ea = *(const float*)(epc + (((unsigned)sa) << 4) + ho) + edn;
        ea = (ea >= 0.f) ? ea : cLEAKY * ea;
        float wa = __builtin_amdgcn_exp2f(ea);
        den += wa;
        float lo, hi;
        unpack2(ra.x, lo, hi); acc[0] += wa * lo; acc[1] += wa * hi;
        unpack2(ra.y, lo, hi); acc[2] += wa * lo; acc[3] += wa * hi;
        unpack2(ra.z, lo, hi); acc[4] += wa * lo; acc[5] += wa * hi;
        unpack2(ra.w, lo, hi); acc[6] += wa * lo; acc[7] += wa * hi;
    }
    float inv = 1.f / (den + 1e-16f);
    float4 b0 = *(const float4*)(bias + 8 * j);
    float4 b1v = *(const float4*)(bias + 8 * j + 4);
    float v0 = acc[0] * inv + b0.x;  r[0] = (v0 > 0.f) ? v0 : expm1f(v0);
    float v1 = acc[1] * inv + b0.y;  r[1] = (v1 > 0.f) ? v1 : expm1f(v1);
    float v2 = acc[2] * inv + b0.z;  r[2] = (v2 > 0.f) ? v2 : expm1f(v2);
    float v3 = acc[3] * inv + b0.w;  r[3] = (v3 > 0.f) ? v3 : expm1f(v3);
    float v4 = acc[4] * inv + b1v.x; r[4] = (v4 > 0.f) ? v4 : expm1f(v4);
    float v5 = acc[5] * inv + b1v.y; r[5] = (v5 > 0.f) ? v5 : expm1f(v5);
    float v6 = acc[6] * inv + b1v.z; r[6] = (v6 > 0.f) ? v6 : expm1f(v6);
    float v7 = acc[7] * inv + b1v.w; r[7] = (v7 > 0.f) ? v7 : expm1f(v7);
}

// ---------------- fused agg(layer1) + GEMM2 + scores2 (single barrier) ----------------
// block = (t, 16 contiguous nodes), t = b&7 (per-XCD plane affinity).
// agg tile -> LDS (XOR-swizzled, pi-v2 order) -> MFMA (W2bP, same K order) ->
// scores via shfl (wave==head) -> direct pi-v2 write of h2 from accumulators.
__global__ __launch_bounds__(256) void agg_gemm_kernel(
        const unsigned short* __restrict__ hb, const float* __restrict__ es,
        const float* __restrict__ ed, const int* __restrict__ offs,
        const int* __restrict__ csr, const float* __restrict__ b1P,
        const unsigned short* __restrict__ W2bP, const float* __restrict__ a_src,
        const float* __restrict__ a_dst, unsigned short* __restrict__ hb2,
        float* __restrict__ es2, float* __restrict__ ed2) {
    __shared__ unsigned short tile[16 * 128];   // 4 KB, XOR-swizzled rows
    int b    = blockIdx.x;
    int t    = b & 7;
    int g    = b >> 3;
    int tid  = threadIdx.x;
    int lrow = tid >> 4;
    int j    = tid & 15;
    int n0   = g * 16;

    float r[8];
    agg_core(hb, es, ed, offs, csr, b1P, t, n0 + lrow, j, r);
    {
        uint4 o;
        o.x = pack2(r[0], r[1]); o.y = pack2(r[2], r[3]);
        o.z = pack2(r[4], r[5]); o.w = pack2(r[6], r[7]);
        unsigned tb = (unsigned)lrow * 256u + (((unsigned)j * 16u) ^ (((unsigned)(lrow & 7)) << 4));
        *(uint4*)((char*)tile + tb) = o;
    }
    __syncthreads();

    // ---- in-block GEMM: h2 = x2 @ W2^T (K=128, pi-v2 order on both sides) ----
    int wave = tid >> 6;
    int lane = tid & 63;
    int q    = lane >> 4;
    int mi   = lane & 15;
    bf16x8 afrag[4];
    #pragma unroll
    for (int s = 0; s < 4; s++) {
        unsigned addr = (unsigned)mi * 256u +
                        (((unsigned)(s * 64 + q * 16)) ^ (((unsigned)(mi & 7)) << 4));
        afrag[s] = *(const bf16x8*)((const char*)tile + addr);
    }
    f32x4 acc2[2];
    acc2[0] = (f32x4){0.f, 0.f, 0.f, 0.f};
    acc2[1] = acc2[0];
    #pragma unroll
    for (int ct = 0; ct < 2; ct++) {
        int c = (wave * 2 + ct) * 16 + mi;
        #pragma unroll
        for (int s = 0; s < 4; s++) {
            bf16x8 bfrag = *(const bf16x8*)(W2bP + (size_t)c * cHID + s * 32 + q * 8);
            acc2[ct] = __builtin_amdgcn_mfma_f32_16x16x32_bf16(afrag[s], bfrag, acc2[ct], 0, 0, 0);
        }
    }

    // ---- scores: wave w owns exactly head w's 32 cols (ct pair 2w,2w+1) ----
    {
        float a0 = a_src[wave * 32 + mi], a1 = a_src[wave * 32 + 16 + mi];
        float d0 = a_dst[wave * 32 + mi], d1 = a_dst[wave * 32 + 16 + mi];
        #pragma unroll
        for (int rr = 0; rr < 4; rr++) {
            float vs = acc2[0][rr] * a0 + acc2[1][rr] * a1;
            float vd = acc2[0][rr] * d0 + acc2[1][rr] * d1;
            vs += __shfl_xor(vs, 1); vs += __shfl_xor(vs, 2);
            vs += __shfl_xor(vs, 4); vs += __shfl_xor(vs, 8);
            vd += __shfl_xor(vd, 1); vd += __shfl_xor(vd, 2);
            vd += __shfl_xor(vd, 4); vd += __shfl_xor(vd, 8);
            if (mi == 0) {
                int rg = t * cN + n0 + q * 4 + rr;
                es2[(size_t)rg * cHEADS + wave] = vs * cL2E;
                ed2[(size_t)rg * cHEADS + wave] = vd * cL2E;
            }
        }
    }

    // ---- direct pi-v2 write of h2: head=wave's pair -> dword wave*16 + mi ----
    #pragma unroll
    for (int rr = 0; rr < 4; rr++) {
        int rg = t * cN + n0 + q * 4 + rr;
        unsigned pv = pack2(acc2[0][rr], acc2[1][rr]);
        *(unsigned*)(hb2 + (size_t)rg * cHID + wave * 32 + mi * 2) = pv;
    }
}

// ---------------- fused agg(layer2) + MLP head -> out ----------------
__global__ __launch_bounds__(256) void TemporalGAT_20005957665499_kernel(
        const unsigned short* __restrict__ hb2, const float* __restrict__ es,
        const float* __restrict__ ed, const int* __restrict__ offs,
        const int* __restrict__ csr, const float* __restrict__ b2P,
        const unsigned short* __restrict__ lw1bP, const float* __restrict__ lb1,
        const float* __restrict__ lw2, const float* __restrict__ lb2,
        float* __restrict__ out) {
    __shared__ unsigned short tile[16 * 128];
    int b    = blockIdx.x;
    int t    = b & 7;
    int g    = b >> 3;
    int tid  = threadIdx.x;
    int lrow = tid >> 4;
    int j    = tid & 15;
    int n0   = g * 16;

    float r[8];
    agg_core(hb2, es, ed, offs, csr, b2P, t, n0 + lrow, j, r);
    {
        uint4 o;
        o.x = pack2(r[0], r[1]); o.y = pack2(r[2], r[3]);
        o.z = pack2(r[4], r[5]); o.w = pack2(r[6], r[7]);
        unsigned tb = (unsigned)lrow * 256u + (((unsigned)j * 16u) ^ (((unsigned)(lrow & 7)) << 4));
        *(uint4*)((char*)tile + tb) = o;
    }
    __syncthreads();

    if (tid < 64) {      // wave 0: 16x128 @ 128x32 MLP (pi-v2 K), then dot with lw2
        int q  = tid >> 4;
        int mi = tid & 15;
        bf16x8 afrag[4];
        #pragma unroll
        for (int s = 0; s < 4; s++) {
            unsigned addr = (unsigned)mi * 256u +
                            (((unsigned)(s * 64 + q * 16)) ^ (((unsigned)(mi & 7)) << 4));
            afrag[s] = *(const bf16x8*)((const char*)tile + addr);
        }
        f32x4 acc2[2];
        acc2[0] = (f32x4){0.f, 0.f, 0.f, 0.f};
        acc2[1] = acc2[0];
        #pragma unroll
        for (int ct = 0; ct < 2; ct++) {
            int c = ct * 16 + mi;
            #pragma unroll
            for (int s = 0; s < 4; s++) {
                bf16x8 bfrag = *(const bf16x8*)(lw1bP + (size_t)c * cHID + s * 32 + q * 8);
                acc2[ct] = __builtin_amdgcn_mfma_f32_16x16x32_bf16(afrag[s], bfrag, acc2[ct], 0, 0, 0);
            }
        }
        float lb1a = lb1[mi], lb1b_ = lb1[16 + mi];
        float lw2a = lw2[mi], lw2b_ = lw2[16 + mi];
        float l2 = lb2[0];
        #pragma unroll
        for (int rr = 0; rr < 4; rr++) {
            float va = fmaxf(acc2[0][rr] + lb1a, 0.f);
            float vb = fmaxf(acc2[1][rr] + lb1b_, 0.f);
            float v = va * lw2a + vb * lw2b_;
            v += __shfl_xor(v, 1);
            v += __shfl_xor(v, 2);
            v += __shfl_xor(v, 4);
            v += __shfl_xor(v, 8);
            if (mi == 0) out[t * cN + n0 + q * 4 + rr] = v + l2;
        }
    }
}

// ---------------- launch ----------------
extern "C" void kernel_launch(void* const* d_in, const int* in_sizes, int n_in,
                              void* d_out, int out_size, void* d_ws, size_t ws_size,
                              hipStream_t stream) {
    const float* x   = (const float*)d_in[0];   // [N,T,64] fp32
    const int*   ei  = (const int*)d_in[1];
    const float* W1  = (const float*)d_in[2];
    const float* as1 = (const float*)d_in[3];
    const float* ad1 = (const float*)d_in[4];
    const float* b1  = (const float*)d_in[5];
    const float* W2  = (const float*)d_in[6];
    const float* as2 = (const float*)d_in[7];
    const float* ad2 = (const float*)d_in[8];
    const float* b2  = (const float*)d_in[9];
    const float* lw1 = (const float*)d_in[10];
    const float* lb1 = (const float*)d_in[11];
    const float* lw2 = (const float*)d_in[12];
    const float* lb2 = (const float*)d_in[13];
    float* out = (float*)d_out;                 // [T,N,1] fp32 == rho-major
    (void)in_sizes; (void)n_in; (void)out_size; (void)ws_size;

    // workspace carve, 256B-aligned
    char* ws = (char*)d_ws;
    size_t o = 0;
    auto carveN = [&](size_t bytes) { void* p = ws + o; o += (bytes + 255) & ~(size_t)255; return p; };
    unsigned short* hb    = (unsigned short*)carveN((size_t)cR * cHID * 2);   // 41 MB (layer-1 h, pi-v2)
    unsigned short* hb2   = (unsigned short*)carveN((size_t)cR * cHID * 2);   // 41 MB (layer-2 h, pi-v2)
    unsigned short* W1b   = (unsigned short*)carveN((size_t)cHID * cFIN * 2);
    unsigned short* W2bP  = (unsigned short*)carveN((size_t)cHID * cHID * 2);
    unsigned short* lw1bP = (unsigned short*)carveN((size_t)cF * cHID * 2);
    float* b1P     = (float*)carveN((size_t)cHID * 4);
    float* b2P     = (float*)carveN((size_t)cHID * 4);
    float* es1_buf = (float*)carveN((size_t)cR * cHEADS * 4);                 // 2.6 MB each
    float* ed1_buf = (float*)carveN((size_t)cR * cHEADS * 4);
    float* es2_buf = (float*)carveN((size_t)cR * cHEADS * 4);
    float* ed2_buf = (float*)carveN((size_t)cR * cHEADS * 4);
    int*   deg     = (int*)carveN((size_t)cN * 4);
    int*   offs    = (int*)carveN((size_t)(cN + 1) * 4);
    int*   cursor  = (int*)carveN((size_t)cN * 4);
    int*   csr     = (int*)carveN((size_t)cET * 4);

    // ---- weight conversion (+pi-v2 permute) + degree count, CSR build ----
    hipMemsetAsync(deg, 0, (size_t)cN * 4, stream);
    cvt_deg_kernel<<<(cE + 255) / 256, 256, 0, stream>>>(
        W1, W2, lw1, b1, b2, ei, W1b, W2bP, lw1bP, b1P, b2P, deg);
    scan_kernel<<<1, 256, 0, stream>>>(deg, offs, cursor);
    scatter_kernel<<<(cET + 255) / 256, 256, 0, stream>>>(ei, cursor, csr);

    // ---- layer 1 GEMM (zero-LDS, direct pi-v2 write, shfl scores) ----
    gemm1_fused_kernel<<<cR / 64, 256, 0, stream>>>(x, W1b, as1, ad1, hb, es1_buf, ed1_buf);
    // ---- agg1 + GEMM2 + scores2 (fused, single barrier) ----
    agg_gemm_kernel<<<(cN / 16) * cT, 256, 0, stream>>>(
        hb, es1_buf, ed1_buf, offs, csr, b1P, W2bP, as2, ad2, hb2, es2_buf, ed2_buf);
    // ---- agg2 + MLP head (fused) -> out ----
    TemporalGAT_20005957665499_kernel<<<(cN / 16) * cT, 256, 0, stream>>>(
        hb2, es2_buf, ed2_buf, offs, csr, b2P, lw1bP, lb1, lw2, lb2, out);
}

// Round 8
// 384.266 us; speedup vs baseline: 1.1390x; 1.0084x over previous
//
#include <hip/hip_runtime.h>

// ---------------- problem constants ----------------
constexpr int cN     = 20000;
constexpr int cT     = 8;
constexpr int cFIN   = 64;
constexpr int cHEADS = 4;
constexpr int cF     = 32;
constexpr int cHID   = 128;        // cHEADS * cF
constexpr int cE     = 320000;
constexpr int cET    = cE + cN;    // edges + self loops
constexpr int cR     = cN * cT;    // 160000 batched rows, rho = t*N + n (t-major)
constexpr int cSCAT  = (cET + 255) / 256;   // scatter blocks in the fused dispatch
constexpr float cLEAKY = 0.2f;
constexpr float cL2E = 1.44269504088896340736f;   // log2(e)

// pi-storage v2 (HEAD-LOCAL): storage dword d = h*16 + mi holds the bf16 pair
// (feature 32h+mi, feature 32h+16+mi). feat(p) = 32*(p>>5) + ((p>>1)&15) + 16*(p&1).
// Head h occupies contiguous bytes [64h, 64h+64) of each 256B row, so an agg
// lane's 16B slice (dwords 4j..4j+3) is entirely within head j>>2.
// MFMA K-permutation is free as long as A and B agree: W2bP/lw1bP/b1P/b2P are
// permuted once at cvt time; h tiles are written directly from accumulators.

typedef __attribute__((ext_vector_type(8))) short bf16x8;   // MFMA A/B frag
typedef __attribute__((ext_vector_type(4))) float f32x4;    // MFMA C/D frag
typedef __attribute__((ext_vector_type(2))) float f32x2;    // packed fp32 (v_pk_fma_f32)

static __device__ __forceinline__ unsigned short f2bfu(float f) {
    unsigned int u;
    __builtin_memcpy(&u, &f, 4);
    u += 0x7FFFu + ((u >> 16) & 1u);
    return (unsigned short)(u >> 16);
}
static __device__ __forceinline__ f32x2 bfp2(unsigned int v) {
    unsigned int ul = v << 16, uh = v & 0xFFFF0000u;
    float lo, hi;
    __builtin_memcpy(&lo, &ul, 4);
    __builtin_memcpy(&hi, &uh, 4);
    return (f32x2){lo, hi};
}
static __device__ __forceinline__ unsigned int pack2(float lo, float hi) {
    unsigned int ul, uh;
    __builtin_memcpy(&ul, &lo, 4);
    __builtin_memcpy(&uh, &hi, 4);
    ul += 0x7FFFu + ((ul >> 16) & 1u);
    uh += 0x7FFFu + ((uh >> 16) & 1u);
    return (ul >> 16) | (uh & 0xFFFF0000u);
}
static __device__ __forceinline__ int featOf(int p) {   // pi-v2 storage -> semantic feature
    return ((p >> 5) << 5) + ((p >> 1) & 15) + ((p & 1) << 4);
}

// ---------------- fused weight conversion (pi-v2 permute) + degree count ----------------
__global__ void cvt_deg_kernel(const float* W1, const float* W2, const float* lw1,
                               const float* b1, const float* b2, const int* ei,
                               unsigned short* W1b, unsigned short* W2bP,
                               unsigned short* lw1bP, float* b1P, float* b2P, int* deg) {
    int i = blockIdx.x * 256 + threadIdx.x;
    if (i < 8192) {                                   // W1b plain (K = x-features, linear)
        W1b[i] = f2bfu(W1[i]);
    } else if (i < 8192 + 16384) {                    // W2bP: K permuted to pi-v2 storage
        int jj = i - 8192;
        int c = jj >> 7, p = jj & 127;
        W2bP[jj] = f2bfu(W2[c * cHID + featOf(p)]);
    } else if (i < 8192 + 16384 + 4096) {             // lw1bP: K permuted
        int jj = i - 8192 - 16384;
        int c = jj >> 7, p = jj & 127;
        lw1bP[jj] = f2bfu(lw1[c * cHID + featOf(p)]);
    } else if (i < 8192 + 16384 + 4096 + 128) {       // b1P
        int p = i - 8192 - 16384 - 4096;
        b1P[p] = b1[featOf(p)];
    } else if (i < 8192 + 16384 + 4096 + 256) {       // b2P
        int p = i - 8192 - 16384 - 4096 - 128;
        b2P[p] = b2[featOf(p)];
    }
    if (i < cE) atomicAdd(&deg[ei[cE + i]], 1);
}

// LDS-staged scan; self-loop (+1) folded into the read.
__global__ void scan_kernel(const int* deg, int* offs, int* cur) {
    __shared__ int sdeg[79 * 256];     // 20224 >= cN
    __shared__ int lds[256];
    int tid = threadIdx.x;
    #pragma unroll 4
    for (int k = 0; k < 79; k++) {
        int idx = k * 256 + tid;
        sdeg[idx] = (idx < cN) ? deg[idx] + 1 : 0;
    }
    __syncthreads();
    const int CH = 79;
    int base = tid * CH;
    int tot = 0;
    #pragma unroll 8
    for (int j = 0; j < CH; j++) tot += sdeg[base + j];
    lds[tid] = tot;
    __syncthreads();
    for (int off = 1; off < 256; off <<= 1) {
        int v = (tid >= off) ? lds[tid - off] : 0;
        __syncthreads();
        lds[tid] += v;
        __syncthreads();
    }
    int run = lds[tid] - tot;
    for (int j = 0; j < CH; j++) {
        int idx = base + j;
        if (idx < cN) { offs[idx] = run; cur[idx] = run; run += sdeg[idx]; }
    }
    if (tid == 255) offs[cN] = lds[255];
}

// ---------------- fused CSR-scatter + GEMM1 (independent work, one dispatch) ----------------
// blocks [0,cSCAT): scatter edges into csr. blocks [cSCAT, cSCAT+cR/64): gemm1.
// gemm1: zero-LDS, direct pi-v2 write, register-shuffle scores.
__global__ __launch_bounds__(256) void scatter_gemm1_kernel(
        const int* __restrict__ ei, int* __restrict__ cur, int* __restrict__ csr,
        const float* __restrict__ x, const unsigned short* __restrict__ W,
        const float* __restrict__ a_src, const float* __restrict__ a_dst,
        unsigned short* __restrict__ hb, float* __restrict__ es, float* __restrict__ ed) {
    int b = blockIdx.x;
    if (b < cSCAT) {
        int e = b * 256 + threadIdx.x;
        if (e >= cET) return;
        int s, d;
        if (e < cE) { s = ei[e]; d = ei[cE + e]; }
        else        { s = e - cE; d = s; }
        int pos = atomicAdd(&cur[d], 1);
        csr[pos] = s;
        return;
    }
    int gb   = b - cSCAT;
    int tid  = threadIdx.x;
    int wave = tid >> 6;
    int lane = tid & 63;
    int q    = lane >> 4;
    int mi   = lane & 15;
    int m0   = gb * 64 + wave * 16;

    int rho = m0 + mi;
    int t = rho / cN;
    int n = rho - t * cN;
    const float* xr = x + (size_t)n * (cT * cFIN) + t * cFIN;

    bf16x8 afrag[2];
    #pragma unroll
    for (int s = 0; s < 2; s++) {
        float4 v0 = *(const float4*)(xr + s * 32 + q * 8);
        float4 v1 = *(const float4*)(xr + s * 32 + q * 8 + 4);
        bf16x8 f;
        f[0] = (short)f2bfu(v0.x); f[1] = (short)f2bfu(v0.y);
        f[2] = (short)f2bfu(v0.z); f[3] = (short)f2bfu(v0.w);
        f[4] = (short)f2bfu(v1.x); f[5] = (short)f2bfu(v1.y);
        f[6] = (short)f2bfu(v1.z); f[7] = (short)f2bfu(v1.w);
        afrag[s] = f;
    }

    f32x4 acc[8];
    #pragma unroll
    for (int ct = 0; ct < 8; ct++) acc[ct] = (f32x4){0.f, 0.f, 0.f, 0.f};
    #pragma unroll
    for (int ct = 0; ct < 8; ct++) {
        int c = ct * 16 + mi;
        #pragma unroll
        for (int s = 0; s < 2; s++) {
            bf16x8 bfrag = *(const bf16x8*)(W + (size_t)c * cFIN + s * 32 + q * 8);
            acc[ct] = __builtin_amdgcn_mfma_f32_16x16x32_bf16(afrag[s], bfrag, acc[ct], 0, 0, 0);
        }
    }

    // scores from accumulators (fp32, no LDS/barrier)
    #pragma unroll
    for (int h = 0; h < 4; h++) {
        float a0 = a_src[h * 32 + mi], a1 = a_src[h * 32 + 16 + mi];
        float d0 = a_dst[h * 32 + mi], d1 = a_dst[h * 32 + 16 + mi];
        #pragma unroll
        for (int rr = 0; rr < 4; rr++) {
            float vs = acc[2 * h][rr] * a0 + acc[2 * h + 1][rr] * a1;
            float vd = acc[2 * h][rr] * d0 + acc[2 * h + 1][rr] * d1;
            vs += __shfl_xor(vs, 1); vs += __shfl_xor(vs, 2);
            vs += __shfl_xor(vs, 4); vs += __shfl_xor(vs, 8);
            vd += __shfl_xor(vd, 1); vd += __shfl_xor(vd, 2);
            vd += __shfl_xor(vd, 4); vd += __shfl_xor(vd, 8);
            if (mi == 0) {
                int rg = m0 + q * 4 + rr;
                es[rg * cHEADS + h] = vs * cL2E;
                ed[rg * cHEADS + h] = vd * cL2E;
            }
        }
    }

    // direct pi-v2 write: head h's pair (32h+mi, 32h+16+mi) -> dword h*16+mi
    #pragma unroll
    for (int rr = 0; rr < 4; rr++) {
        int rg = m0 + q * 4 + rr;
        unsigned short* hrow = hb + (size_t)rg * cHID;
        #pragma unroll
        for (int h = 0; h < 4; h++) {
            unsigned pv = pack2(acc[2 * h][rr], acc[2 * h + 1][rr]);
            *(unsigned*)(hrow + h * 32 + mi * 2) = pv;
        }
    }
}

// ---------------- agg core: one (row, 8-feature slice) per thread, packed fp32 ----------------
// Slice j = storage bytes [16j,16j+16) == head j>>2 only (pi-v2 head-locality).
// scores es/ed pre-scaled by log2(e); w = exp2(leaky(es+ed)).
// f32x2 accumulators -> v_pk_fma_f32: per dword 2 bit-ops + 1 pk_fma (was 2 unpack + 2 fma).
static __device__ __forceinline__ void agg_core(
        const unsigned short* __restrict__ hb, const float* __restrict__ es,
        const float* __restrict__ ed, const int* __restrict__ offs,
        const int* __restrict__ csr, const float* __restrict__ bias,
        int t, int n, int j, float* r) {
    int head = j >> 2;
    int rho  = t * cN + n;
    int s0 = offs[n], s1 = offs[n + 1];
    float edn = ed[(size_t)rho * cHEADS + head];
    const char* hpc = (const char*)(hb + (size_t)t * cN * cHID);     // plane base
    const char* epc = (const char*)(es + (size_t)t * cN * cHEADS);
    const char* cc  = (const char*)csr;
    unsigned jo = (unsigned)j * 16u;
    unsigned ho = (unsigned)head * 4u;

    f32x2 acc[4];
    #pragma unroll
    for (int k = 0; k < 4; k++) acc[k] = (f32x2){0.f, 0.f};
    float den = 0.f;
    int i = s0;
    for (; i + 3 < s1; i += 4) {
        unsigned io = (unsigned)i * 4u;
        int sa = *(const int*)(cc + io);
        int sb = *(const int*)(cc + io + 4u);
        int sc = *(const int*)(cc + io + 8u);
        int sd = *(const int*)(cc + io + 12u);
        uint4 ra = *(const uint4*)(hpc + (((unsigned)sa) << 8) + jo);
        uint4 rb = *(const uint4*)(hpc + (((unsigned)sb) << 8) + jo);
        uint4 rc = *(const uint4*)(hpc + (((unsigned)sc) << 8) + jo);
        uint4 rd = *(const uint4*)(hpc + (((unsigned)sd) << 8) + jo);
        float ea = *(const float*)(epc + (((unsigned)sa) << 4) + ho) + edn;
        float eb = *(const float*)(epc + (((unsigned)sb) << 4) + ho) + edn;
        float ec = *(const float*)(epc + (((unsigned)sc) << 4) + ho) + edn;
        float ee = *(const float*)(epc + (((unsigned)sd) << 4) + ho) + edn;
        ea = (ea >= 0.f) ? ea : cLEAKY * ea;
        eb = (eb >= 0.f) ? eb : cLEAKY * eb;
        ec = (ec >= 0.f) ? ec : cLEAKY * ec;
        ee = (ee >= 0.f) ? ee : cLEAKY * ee;
        float wa = __builtin_amdgcn_exp2f(ea), wb = __builtin_amdgcn_exp2f(eb);
        float wc = __builtin_amdgcn_exp2f(ec), wd = __builtin_amdgcn_exp2f(ee);
        den += wa; den += wb; den += wc; den += wd;
        f32x2 wa2 = (f32x2){wa, wa}, wb2 = (f32x2){wb, wb};
        f32x2 wc2 = (f32x2){wc, wc}, wd2 = (f32x2){wd, wd};
        acc[0] += wa2 * bfp2(ra.x); acc[1] += wa2 * bfp2(ra.y);
        acc[2] += wa2 * bfp2(ra.z); acc[3] += wa2 * bfp2(ra.w);
        acc[0] += wb2 * bfp2(rb.x); acc[1] += wb2 * bfp2(rb.y);
        acc[2] += wb2 * bfp2(rb.z); acc[3] += wb2 * bfp2(rb.w);
        acc[0] += wc2 * bfp2(rc.x); acc[1] += wc2 * bfp2(rc.y);
        acc[2] += wc2 * bfp2(rc.z); acc[3] += wc2 * bfp2(rc.w);
        acc[0] += wd2 * bfp2(rd.x); acc[1] += wd2 * bfp2(rd.y);
        acc[2] += wd2 * bfp2(rd.z); acc[3] += wd2 * bfp2(rd.w);
    }
    for (; i < s1; i++) {
        int sa = *(const int*)(cc + (unsigned)i * 4u);
        uint4 ra = *(const uint4*)(hpc + (((unsigned)sa) << 8) + jo);
        float ea = *(const float*)(epc + (((unsigned)sa) << 4) + ho) + edn;
        ea = (ea >= 0.f) ? ea : cLEAKY * ea;
        float wa = __builtin_amdgcn_exp2f(ea);
        den += wa;
        f32x2 wa2 = (f32x2){wa, wa};
        acc[0] += wa2 * bfp2(ra.x); acc[1] += wa2 * bfp2(ra.y);
        acc[2] += wa2 * bfp2(ra.z); acc[3] += wa2 * bfp2(ra.w);
    }
    float inv = 1.f / (den + 1e-16f);
    float4 b0 = *(const float4*)(bias + 8 * j);
    float4 b1v = *(const float4*)(bias + 8 * j + 4);
    float v0 = acc[0].x * inv + b0.x;  r[0] = (v0 > 0.f) ? v0 : expm1f(v0);
    float v1 = acc[0].y * inv + b0.y;  r[1] = (v1 > 0.f) ? v1 : expm1f(v1);
    float v2 = acc[1].x * inv + b0.z;  r[2] = (v2 > 0.f) ? v2 : expm1f(v2);
    float v3 = acc[1].y * inv + b0.w;  r[3] = (v3 > 0.f) ? v3 : expm1f(v3);
    float v4 = acc[2].x * inv + b1v.x; r[4] = (v4 > 0.f) ? v4 : expm1f(v4);
    float v5 = acc[2].y * inv + b1v.y; r[5] = (v5 > 0.f) ? v5 : expm1f(v5);
    float v6 = acc[3].x * inv + b1v.z; r[6] = (v6 > 0.f) ? v6 : expm1f(v6);
    float v7 = acc[3].y * inv + b1v.w; r[7] = (v7 > 0.f) ? v7 : expm1f(v7);
}

// ---------------- fused agg(layer1) + GEMM2 + scores2 (single barrier) ----------------
// block = (t, 16 contiguous nodes), t = b&7 (per-XCD plane affinity).
__global__ __launch_bounds__(256) void agg_gemm_kernel(
        const unsigned short* __restrict__ hb, const float* __restrict__ es,
        const float* __restrict__ ed, const int* __restrict__ offs,
        const int* __restrict__ csr, const float* __restrict__ b1P,
        const unsigned short* __restrict__ W2bP, const float* __restrict__ a_src,
        const float* __restrict__ a_dst, unsigned short* __restrict__ hb2,
        float* __restrict__ es2, float* __restrict__ ed2) {
    __shared__ unsigned short tile[16 * 128];   // 4 KB, XOR-swizzled rows
    int b    = blockIdx.x;
    int t    = b & 7;
    int g    = b >> 3;
    int tid  = threadIdx.x;
    int lrow = tid >> 4;
    int j    = tid & 15;
    int n0   = g * 16;

    float r[8];
    agg_core(hb, es, ed, offs, csr, b1P, t, n0 + lrow, j, r);
    {
        uint4 o;
        o.x = pack2(r[0], r[1]); o.y = pack2(r[2], r[3]);
        o.z = pack2(r[4], r[5]); o.w = pack2(r[6], r[7]);
        unsigned tb = (unsigned)lrow * 256u + (((unsigned)j * 16u) ^ (((unsigned)(lrow & 7)) << 4));
        *(uint4*)((char*)tile + tb) = o;
    }
    __syncthreads();

    // ---- in-block GEMM: h2 = x2 @ W2^T (K=128, pi-v2 order on both sides) ----
    int wave = tid >> 6;
    int lane = tid & 63;
    int q    = lane >> 4;
    int mi   = lane & 15;
    bf16x8 afrag[4];
    #pragma unroll
    for (int s = 0; s < 4; s++) {
        unsigned addr = (unsigned)mi * 256u +
                        (((unsigned)(s * 64 + q * 16)) ^ (((unsigned)(mi & 7)) << 4));
        afrag[s] = *(const bf16x8*)((const char*)tile + addr);
    }
    f32x4 acc2[2];
    acc2[0] = (f32x4){0.f, 0.f, 0.f, 0.f};
    acc2[1] = acc2[0];
    #pragma unroll
    for (int ct = 0; ct < 2; ct++) {
        int c = (wave * 2 + ct) * 16 + mi;
        #pragma unroll
        for (int s = 0; s < 4; s++) {
            bf16x8 bfrag = *(const bf16x8*)(W2bP + (size_t)c * cHID + s * 32 + q * 8);
            acc2[ct] = __builtin_amdgcn_mfma_f32_16x16x32_bf16(afrag[s], bfrag, acc2[ct], 0, 0, 0);
        }
    }

    // ---- scores: wave w owns exactly head w's 32 cols (ct pair 2w,2w+1) ----
    {
        float a0 = a_src[wave * 32 + mi], a1 = a_src[wave * 32 + 16 + mi];
        float d0 = a_dst[wave * 32 + mi], d1 = a_dst[wave * 32 + 16 + mi];
        #pragma unroll
        for (int rr = 0; rr < 4; rr++) {
            float vs = acc2[0][rr] * a0 + acc2[1][rr] * a1;
            float vd = acc2[0][rr] * d0 + acc2[1][rr] * d1;
            vs += __shfl_xor(vs, 1); vs += __shfl_xor(vs, 2);
            vs += __shfl_xor(vs, 4); vs += __shfl_xor(vs, 8);
            vd += __shfl_xor(vd, 1); vd += __shfl_xor(vd, 2);
            vd += __shfl_xor(vd, 4); vd += __shfl_xor(vd, 8);
            if (mi == 0) {
                int rg = t * cN + n0 + q * 4 + rr;
                es2[(size_t)rg * cHEADS + wave] = vs * cL2E;
                ed2[(size_t)rg * cHEADS + wave] = vd * cL2E;
            }
        }
    }

    // ---- direct pi-v2 write of h2: head=wave's pair -> dword wave*16 + mi ----
    #pragma unroll
    for (int rr = 0; rr < 4; rr++) {
        int rg = t * cN + n0 + q * 4 + rr;
        unsigned pv = pack2(acc2[0][rr], acc2[1][rr]);
        *(unsigned*)(hb2 + (size_t)rg * cHID + wave * 32 + mi * 2) = pv;
    }
}

// ---------------- fused agg(layer2) + MLP head -> out ----------------
__global__ __launch_bounds__(256) void TemporalGAT_20005957665499_kernel(
        const unsigned short* __restrict__ hb2, const float* __restrict__ es,
        const float* __restrict__ ed, const int* __restrict__ offs,
        const int* __restrict__ csr, const float* __restrict__ b2P,
        const unsigned short* __restrict__ lw1bP, const float* __restrict__ lb1,
        const float* __restrict__ lw2, const float* __restrict__ lb2,
        float* __restrict__ out) {
    __shared__ unsigned short tile[16 * 128];
    int b    = blockIdx.x;
    int t    = b & 7;
    int g    = b >> 3;
    int tid  = threadIdx.x;
    int lrow = tid >> 4;
    int j    = tid & 15;
    int n0   = g * 16;

    float r[8];
    agg_core(hb2, es, ed, offs, csr, b2P, t, n0 + lrow, j, r);
    {
        uint4 o;
        o.x = pack2(r[0], r[1]); o.y = pack2(r[2], r[3]);
        o.z = pack2(r[4], r[5]); o.w = pack2(r[6], r[7]);
        unsigned tb = (unsigned)lrow * 256u + (((unsigned)j * 16u) ^ (((unsigned)(lrow & 7)) << 4));
        *(uint4*)((char*)tile + tb) = o;
    }
    __syncthreads();

    if (tid < 64) {      // wave 0: 16x128 @ 128x32 MLP (pi-v2 K), then dot with lw2
        int q  = tid >> 4;
        int mi = tid & 15;
        bf16x8 afrag[4];
        #pragma unroll
        for (int s = 0; s < 4; s++) {
            unsigned addr = (unsigned)mi * 256u +
                            (((unsigned)(s * 64 + q * 16)) ^ (((unsigned)(mi & 7)) << 4));
            afrag[s] = *(const bf16x8*)((const char*)tile + addr);
        }
        f32x4 acc2[2];
        acc2[0] = (f32x4){0.f, 0.f, 0.f, 0.f};
        acc2[1] = acc2[0];
        #pragma unroll
        for (int ct = 0; ct < 2; ct++) {
            int c = ct * 16 + mi;
            #pragma unroll
            for (int s = 0; s < 4; s++) {
                bf16x8 bfrag = *(const bf16x8*)(lw1bP + (size_t)c * cHID + s * 32 + q * 8);
                acc2[ct] = __builtin_amdgcn_mfma_f32_16x16x32_bf16(afrag[s], bfrag, acc2[ct], 0, 0, 0);
            }
        }
        float lb1a = lb1[mi], lb1b_ = lb1[16 + mi];
        float lw2a = lw2[mi], lw2b_ = lw2[16 + mi];
        float l2 = lb2[0];
        #pragma unroll
        for (int rr = 0; rr < 4; rr++) {
            float va = fmaxf(acc2[0][rr] + lb1a, 0.f);
            float vb = fmaxf(acc2[1][rr] + lb1b_, 0.f);
            float v = va * lw2a + vb * lw2b_;
            v += __shfl_xor(v, 1);
            v += __shfl_xor(v, 2);
            v += __shfl_xor(v, 4);
            v += __shfl_xor(v, 8);
            if (mi == 0) out[t * cN + n0 + q * 4 + rr] = v + l2;
        }
    }
}

// ---------------- launch ----------------
extern "C" void kernel_launch(void* const* d_in, const int* in_sizes, int n_in,
                              void* d_out, int out_size, void* d_ws, size_t ws_size,
                              hipStream_t stream) {
    const float* x   = (const float*)d_in[0];   // [N,T,64] fp32
    const int*   ei  = (const int*)d_in[1];
    const float* W1  = (const float*)d_in[2];
    const float* as1 = (const float*)d_in[3];
    const float* ad1 = (const float*)d_in[4];
    const float* b1  = (const float*)d_in[5];
    const float* W2  = (const float*)d_in[6];
    const float* as2 = (const float*)d_in[7];
    const float* ad2 = (const float*)d_in[8];
    const float* b2  = (const float*)d_in[9];
    const float* lw1 = (const float*)d_in[10];
    const float* lb1 = (const float*)d_in[11];
    const float* lw2 = (const float*)d_in[12];
    const float* lb2 = (const float*)d_in[13];
    float* out = (float*)d_out;                 // [T,N,1] fp32 == rho-major
    (void)in_sizes; (void)n_in; (void)out_size; (void)ws_size;

    // workspace carve, 256B-aligned
    char* ws = (char*)d_ws;
    size_t o = 0;
    auto carveN = [&](size_t bytes) { void* p = ws + o; o += (bytes + 255) & ~(size_t)255; return p; };
    unsigned short* hb    = (unsigned short*)carveN((size_t)cR * cHID * 2);   // 41 MB (layer-1 h, pi-v2)
    unsigned short* hb2   = (unsigned short*)carveN((size_t)cR * cHID * 2);   // 41 MB (layer-2 h, pi-v2)
    unsigned short* W1b   = (unsigned short*)carveN((size_t)cHID * cFIN * 2);
    unsigned short* W2bP  = (unsigned short*)carveN((size_t)cHID * cHID * 2);
    unsigned short* lw1bP = (unsigned short*)carveN((size_t)cF * cHID * 2);
    float* b1P     = (float*)carveN((size_t)cHID * 4);
    float* b2P     = (float*)carveN((size_t)cHID * 4);
    float* es1_buf = (float*)carveN((size_t)cR * cHEADS * 4);                 // 2.6 MB each
    float* ed1_buf = (float*)carveN((size_t)cR * cHEADS * 4);
    float* es2_buf = (float*)carveN((size_t)cR * cHEADS * 4);
    float* ed2_buf = (float*)carveN((size_t)cR * cHEADS * 4);
    int*   deg     = (int*)carveN((size_t)cN * 4);
    int*   offs    = (int*)carveN((size_t)(cN + 1) * 4);
    int*   cursor  = (int*)carveN((size_t)cN * 4);
    int*   csr     = (int*)carveN((size_t)cET * 4);

    // ---- weight conversion (+pi-v2 permute) + degree count ----
    hipMemsetAsync(deg, 0, (size_t)cN * 4, stream);
    cvt_deg_kernel<<<(cE + 255) / 256, 256, 0, stream>>>(
        W1, W2, lw1, b1, b2, ei, W1b, W2bP, lw1bP, b1P, b2P, deg);
    scan_kernel<<<1, 256, 0, stream>>>(deg, offs, cursor);
    // ---- CSR scatter + layer-1 GEMM (independent work, one dispatch) ----
    scatter_gemm1_kernel<<<cSCAT + cR / 64, 256, 0, stream>>>(
        ei, cursor, csr, x, W1b, as1, ad1, hb, es1_buf, ed1_buf);
    // ---- agg1 + GEMM2 + scores2 (fused, single barrier, packed-fp32 gather) ----
    agg_gemm_kernel<<<(cN / 16) * cT, 256, 0, stream>>>(
        hb, es1_buf, ed1_buf, offs, csr, b1P, W2bP, as2, ad2, hb2, es2_buf, ed2_buf);
    // ---- agg2 + MLP head (fused) -> out ----
    TemporalGAT_20005957665499_kernel<<<(cN / 16) * cT, 256, 0, stream>>>(
        hb2, es2_buf, ed2_buf, offs, csr, b2P, lw1bP, lb1, lw2, lb2, out);
}